// Round 1
// baseline (2160.487 us; speedup 1.0000x reference)
//
#include <hip/hip_runtime.h>
#include <math.h>

#define TD 1024      // model dim
#define NH 16        // heads
#define HDIM 64      // head dim
#define SEQ 2048     // seq len
#define NB 2         // batch
#define NROWS 4096   // NB*SEQ
#define FFD 4096     // ffn dim

// ---------------- LayerNorm: one block (256 thr) per row of 1024 ----------------
__global__ __launch_bounds__(256) void ln_kernel(const float* __restrict__ x,
                                                 const float* __restrict__ g,
                                                 const float* __restrict__ b,
                                                 float* __restrict__ out)
{
    int row = blockIdx.x;
    const float* xr = x + (size_t)row * TD;
    float* outr = out + (size_t)row * TD;
    int t = threadIdx.x;
    float v[4];
    float s = 0.f, ss = 0.f;
#pragma unroll
    for (int i = 0; i < 4; i++) {
        v[i] = xr[t + 256 * i];
        s += v[i];
        ss += v[i] * v[i];
    }
#pragma unroll
    for (int o = 32; o > 0; o >>= 1) {
        s  += __shfl_down(s, o);
        ss += __shfl_down(ss, o);
    }
    __shared__ float sm[4], sm2[4];
    int wave = t >> 6, lane = t & 63;
    if (lane == 0) { sm[wave] = s; sm2[wave] = ss; }
    __syncthreads();
    s  = sm[0] + sm[1] + sm[2] + sm[3];
    ss = sm2[0] + sm2[1] + sm2[2] + sm2[3];
    float mu  = s * (1.f / TD);
    float var = ss * (1.f / TD) - mu * mu;
    float rstd = rsqrtf(var + 1e-5f);
#pragma unroll
    for (int i = 0; i < 4; i++) {
        int c = t + 256 * i;
        outr[c] = (v[i] - mu) * rstd * g[c] + b[c];
    }
}

// ---------------- fp32 tiled GEMM: C[M,N] = A[M,K] @ B[K,N] + bias (+epi) ------
// EPI: 0 = bias only; 1 = bias + residual add; 2 = bias + exact GELU
template<int EPI>
__global__ __launch_bounds__(256) void gemm_kernel(int M, int N, int K,
    const float* __restrict__ A, const float* __restrict__ Bm,
    const float* __restrict__ bias, const float* __restrict__ res,
    float* __restrict__ C)
{
    // stride 68 floats = 272 B -> 16B-aligned rows for ds_read_b128, odd*4 banks
    __shared__ float As[16][68];   // [k][m]
    __shared__ float Bs[16][68];   // [k][n]
    int t = threadIdx.x;
    int tx = t & 15, ty = t >> 4;
    int n0 = blockIdx.x * 64, m0 = blockIdx.y * 64;
    float acc[4][4] = {};
    int ar = t >> 2, ak = (t & 3) * 4;     // A: 4 lanes per row, float4 along K
    int bk = t >> 4, bc = (t & 15) * 4;    // B: 16 lanes per row, float4 along N
    const float* Aptr = A + (size_t)(m0 + ar) * K + ak;
    const float* Bptr = Bm + (size_t)bk * N + n0 + bc;
    for (int k0 = 0; k0 < K; k0 += 16) {
        float4 av = *(const float4*)(Aptr + k0);
        float4 bv = *(const float4*)(Bptr + (size_t)k0 * N);
        As[ak + 0][ar] = av.x;
        As[ak + 1][ar] = av.y;
        As[ak + 2][ar] = av.z;
        As[ak + 3][ar] = av.w;
        *(float4*)&Bs[bk][bc] = bv;
        __syncthreads();
#pragma unroll
        for (int kk = 0; kk < 16; kk++) {
            float4 a4 = *(const float4*)&As[kk][ty * 4];
            float4 b4 = *(const float4*)&Bs[kk][tx * 4];
            float a[4]  = { a4.x, a4.y, a4.z, a4.w };
            float bb[4] = { b4.x, b4.y, b4.z, b4.w };
#pragma unroll
            for (int i = 0; i < 4; i++)
#pragma unroll
                for (int j = 0; j < 4; j++)
                    acc[i][j] = fmaf(a[i], bb[j], acc[i][j]);
        }
        __syncthreads();
    }
#pragma unroll
    for (int i = 0; i < 4; i++) {
        int r = m0 + ty * 4 + i;
#pragma unroll
        for (int j = 0; j < 4; j++) {
            int c = n0 + tx * 4 + j;
            float v = acc[i][j] + bias[c];
            if (EPI == 1) v += res[(size_t)r * N + c];
            if (EPI == 2) v = 0.5f * v * (1.f + erff(v * 0.70710678118654752f));
            C[(size_t)r * N + c] = v;
        }
    }
}

// ---------------- causal flash attention, fp32, 64x64 tiles --------------------
// qkv layout: [(b*SEQ + t)*3072 + comp*1024 + h*64 + d], comp in {q,k,v}
// ctx layout: [(b*SEQ + t)*1024 + h*64 + d]
__global__ __launch_bounds__(256) void attn_kernel(const float* __restrict__ qkv,
                                                   float* __restrict__ ctx)
{
    __shared__ float Qs[64][68];   // [dim][qrow]
    __shared__ float Ks[64][68];   // [dim][krow]
    __shared__ float Vs[64][68];   // [krow][dim]
    __shared__ float Ss[64][68];   // [kcol][qrow]  (transposed scores/probs)
    __shared__ float mrow[64], lrow[64], arow[64];
    int qt = blockIdx.x;           // 0..31
    int bh = blockIdx.y;           // 0..31
    int bb = bh >> 4, h = bh & 15;
    int t = threadIdx.x;
    int tx = t & 15, ty = t >> 4;
    const float scale = 0.125f;    // 1/sqrt(64)

    size_t qbase = (size_t)(bb * SEQ + qt * 64) * 3072 + h * 64;
#pragma unroll
    for (int i = 0; i < 16; i++) {
        int idx = t + 256 * i;
        int r = idx >> 6, d = idx & 63;
        Qs[d][r] = qkv[qbase + (size_t)r * 3072 + d];
    }
    if (t < 64) { mrow[t] = -INFINITY; lrow[t] = 0.f; }
    float o[4][4] = {};
    __syncthreads();

    for (int kt = 0; kt <= qt; kt++) {
        size_t kbase = (size_t)(bb * SEQ + kt * 64) * 3072 + h * 64;
#pragma unroll
        for (int i = 0; i < 16; i++) {
            int idx = t + 256 * i;
            int r = idx >> 6, d = idx & 63;
            Ks[d][r] = qkv[kbase + (size_t)r * 3072 + 1024 + d];
            Vs[r][d] = qkv[kbase + (size_t)r * 3072 + 2048 + d];
        }
        __syncthreads();

        // S = Q K^T, 4x4 per thread
        float s[4][4] = {};
        for (int kk = 0; kk < 64; kk++) {
            float4 a4 = *(const float4*)&Qs[kk][ty * 4];
            float4 b4 = *(const float4*)&Ks[kk][tx * 4];
            float a[4]  = { a4.x, a4.y, a4.z, a4.w };
            float bq[4] = { b4.x, b4.y, b4.z, b4.w };
#pragma unroll
            for (int i = 0; i < 4; i++)
#pragma unroll
                for (int j = 0; j < 4; j++)
                    s[i][j] = fmaf(a[i], bq[j], s[i][j]);
        }
        bool diag = (kt == qt);
#pragma unroll
        for (int j = 0; j < 4; j++) {
            int c = tx * 4 + j;
            float4 sc;
            float* scp = &sc.x;
#pragma unroll
            for (int i = 0; i < 4; i++) {
                int r = ty * 4 + i;
                float sv = s[i][j] * scale;
                if (diag && c > r) sv = -INFINITY;
                scp[i] = sv;
            }
            *(float4*)&Ss[c][ty * 4] = sc;
        }
        __syncthreads();

        // online softmax: one thread per query row
        if (t < 64) {
            int r = t;
            float mold = mrow[r];
            float mnew = mold;
            for (int c = 0; c < 64; c++) mnew = fmaxf(mnew, Ss[c][r]);
            float alpha = expf(mold - mnew);   // mold=-inf -> 0
            float l = lrow[r] * alpha;
            for (int c = 0; c < 64; c++) {
                float p = expf(Ss[c][r] - mnew);
                Ss[c][r] = p;
                l += p;
            }
            mrow[r] = mnew; lrow[r] = l; arow[r] = alpha;
        }
        __syncthreads();

        // O = alpha*O + P V
        float al[4];
#pragma unroll
        for (int i = 0; i < 4; i++) al[i] = arow[ty * 4 + i];
#pragma unroll
        for (int i = 0; i < 4; i++)
#pragma unroll
            for (int j = 0; j < 4; j++) o[i][j] *= al[i];
        for (int c = 0; c < 64; c++) {
            float4 p4 = *(const float4*)&Ss[c][ty * 4];
            float4 v4 = *(const float4*)&Vs[c][tx * 4];
            float p[4]  = { p4.x, p4.y, p4.z, p4.w };
            float vv[4] = { v4.x, v4.y, v4.z, v4.w };
#pragma unroll
            for (int i = 0; i < 4; i++)
#pragma unroll
                for (int j = 0; j < 4; j++)
                    o[i][j] = fmaf(p[i], vv[j], o[i][j]);
        }
        __syncthreads();
    }

#pragma unroll
    for (int i = 0; i < 4; i++) {
        int r = ty * 4 + i;
        float inv = 1.f / lrow[r];
        int qi = qt * 64 + r;
        float4 ov;
        ov.x = o[i][0] * inv; ov.y = o[i][1] * inv;
        ov.z = o[i][2] * inv; ov.w = o[i][3] * inv;
        *(float4*)&ctx[(size_t)(bb * SEQ + qi) * TD + h * 64 + tx * 4] = ov;
    }
}

extern "C" void kernel_launch(void* const* d_in, const int* in_sizes, int n_in,
                              void* d_out, int out_size, void* d_ws, size_t ws_size,
                              hipStream_t stream)
{
    const float* x    = (const float*)d_in[0];
    const float* g1   = (const float*)d_in[1];
    const float* b1   = (const float*)d_in[2];
    const float* Wqkv = (const float*)d_in[3];
    const float* bqkv = (const float*)d_in[4];
    const float* Wo   = (const float*)d_in[5];
    const float* bo   = (const float*)d_in[6];
    const float* g2   = (const float*)d_in[7];
    const float* b2   = (const float*)d_in[8];
    const float* W1   = (const float*)d_in[9];
    const float* b1f  = (const float*)d_in[10];
    const float* W2   = (const float*)d_in[11];
    const float* b2f  = (const float*)d_in[12];
    float* out = (float*)d_out;

    char* ws = (char*)d_ws;
    float* bufA = (float*)(ws);                          // 64 MiB: qkv (48M) then ff1 (64M)
    float* bufB = (float*)(ws + ((size_t)64 << 20));     // 16 MiB: h then hh
    float* bufC = (float*)(ws + ((size_t)80 << 20));     // 16 MiB: attn ctx
    float* bufD = (float*)(ws + ((size_t)96 << 20));     // 16 MiB: x2 (post-attn residual)

    // h = LN(x)
    ln_kernel<<<NROWS, 256, 0, stream>>>(x, g1, b1, bufB);
    // qkv = h @ Wqkv + bqkv
    gemm_kernel<0><<<dim3(3 * TD / 64, NROWS / 64), 256, 0, stream>>>(
        NROWS, 3 * TD, TD, bufB, Wqkv, bqkv, nullptr, bufA);
    // ctx = causal_attention(qkv)
    attn_kernel<<<dim3(SEQ / 64, NB * NH), 256, 0, stream>>>(bufA, bufC);
    // x2 = x + ctx @ Wo + bo
    gemm_kernel<1><<<dim3(TD / 64, NROWS / 64), 256, 0, stream>>>(
        NROWS, TD, TD, bufC, Wo, bo, x, bufD);
    // hh = LN(x2)
    ln_kernel<<<NROWS, 256, 0, stream>>>(bufD, g2, b2, bufB);
    // ff1 = gelu(hh @ W1 + b1f)
    gemm_kernel<2><<<dim3(FFD / 64, NROWS / 64), 256, 0, stream>>>(
        NROWS, FFD, TD, bufB, W1, b1f, nullptr, bufA);
    // out = x2 + ff1 @ W2 + b2f
    gemm_kernel<1><<<dim3(TD / 64, NROWS / 64), 256, 0, stream>>>(
        NROWS, TD, FFD, bufA, W2, b2f, bufD, out);
}

// Round 2
// 530.909 us; speedup vs baseline: 4.0694x; 4.0694x over previous
//
#include <hip/hip_runtime.h>
#include <math.h>

#define TD 1024      // model dim
#define NH 16        // heads
#define HDIM 64      // head dim
#define SEQ 2048     // seq len
#define NB 2         // batch
#define NROWS 4096   // NB*SEQ
#define FFD 4096     // ffn dim

typedef unsigned short u16;
typedef __attribute__((ext_vector_type(8))) short bf16x8;   // 8 bf16 = 4 VGPR
typedef __attribute__((ext_vector_type(4))) float f32x4;    // MFMA acc

__device__ __forceinline__ u16 f2bf(float f) {
    union { float f; unsigned u; } v; v.f = f;
    return (u16)((v.u + 0x7FFFu + ((v.u >> 16) & 1u)) >> 16);
}

// async global->LDS, 16B per lane. LDS dest must be wave-uniform base + lane*16.
__device__ __forceinline__ void async16(void* lds, const void* g) {
    __builtin_amdgcn_global_load_lds(
        (const __attribute__((address_space(1))) unsigned*)g,
        (__attribute__((address_space(3))) unsigned*)lds, 16, 0, 0);
}

// ---------------- LayerNorm -> bf16 out: one block per row of 1024 -------------
__global__ __launch_bounds__(256) void ln_bf16(const float* __restrict__ x,
                                               const float* __restrict__ g,
                                               const float* __restrict__ b,
                                               u16* __restrict__ out)
{
    int row = blockIdx.x;
    const float* xr = x + (size_t)row * TD;
    u16* outr = out + (size_t)row * TD;
    int t = threadIdx.x;
    float v[4];
    float s = 0.f, ss = 0.f;
#pragma unroll
    for (int i = 0; i < 4; i++) {
        v[i] = xr[t + 256 * i];
        s += v[i];
        ss += v[i] * v[i];
    }
#pragma unroll
    for (int o = 32; o > 0; o >>= 1) {
        s  += __shfl_down(s, o);
        ss += __shfl_down(ss, o);
    }
    __shared__ float sm[4], sm2[4];
    int wave = t >> 6, lane = t & 63;
    if (lane == 0) { sm[wave] = s; sm2[wave] = ss; }
    __syncthreads();
    s  = sm[0] + sm[1] + sm[2] + sm[3];
    ss = sm2[0] + sm2[1] + sm2[2] + sm2[3];
    float mu  = s * (1.f / TD);
    float var = ss * (1.f / TD) - mu * mu;
    float rstd = rsqrtf(var + 1e-5f);
#pragma unroll
    for (int i = 0; i < 4; i++) {
        int c = t + 256 * i;
        outr[c] = f2bf((v[i] - mu) * rstd * g[c] + b[c]);
    }
}

// ---------------- weight convert+transpose: W[K][N] fp32 -> Wt[N][K] bf16 ------
__global__ __launch_bounds__(256) void wconv_t(const float* __restrict__ W,
                                               u16* __restrict__ Wt, int K, int N)
{
    __shared__ u16 tile[64][65];
    int n0 = blockIdx.x * 64, k0 = blockIdx.y * 64;
    int t = threadIdx.x, c = t & 63, rq = t >> 6;
#pragma unroll
    for (int i = 0; i < 16; i++) {
        int r = rq * 16 + i;
        tile[r][c] = f2bf(W[(size_t)(k0 + r) * N + n0 + c]);
    }
    __syncthreads();
#pragma unroll
    for (int i = 0; i < 16; i++) {
        int r = rq * 16 + i;
        Wt[(size_t)(n0 + r) * K + k0 + c] = tile[c][r];
    }
}

// ---------------- bf16 MFMA GEMM, 128x128 tile, BK=32 --------------------------
// C[M,N] = A[M,K] @ Bt[N,K]^T + bias, with epilogues.
// EPI 0: QKV split-scatter (Q/K [bh][seq][64], V transposed [bh][64][seq])
// EPI 1: fp32 out + residual add
// EPI 2: bf16 out + exact GELU
#define EPI_QKV 0
#define EPI_F32RES 1
#define EPI_GELU 2

template<int EPI>
__global__ __launch_bounds__(256) void gemm_mfma(int M, int N, int K,
    const u16* __restrict__ A, const u16* __restrict__ Bt,
    const float* __restrict__ bias, const float* __restrict__ res,
    float* __restrict__ Cf, u16* __restrict__ Cb,
    u16* __restrict__ qb, u16* __restrict__ kb, u16* __restrict__ vb)
{
    __shared__ __align__(16) u16 As[128 * 32];   // [m][k] row-major, 64B rows
    __shared__ __align__(16) u16 Bs[128 * 32];   // [n][k] row-major
    int t = threadIdx.x;
    int lane = t & 63, w = t >> 6;
    int wm = w >> 1, wn = w & 1;          // 2x2 wave grid, each wave 64x64
    int lr = lane & 15, lq = lane >> 4;
    int m0 = blockIdx.y * 128, n0 = blockIdx.x * 128;

    // staging: chunk c (16B) = row c>>2, k8 c&3. c0=t, c1=t+256.
    const u16* a0 = A + (size_t)(m0 + (t >> 2)) * K + (t & 3) * 8;
    const u16* a1 = a0 + (size_t)64 * K;
    const u16* b0 = Bt + (size_t)(n0 + (t >> 2)) * K + (t & 3) * 8;
    const u16* b1 = b0 + (size_t)64 * K;
    char* AsB = (char*)As;
    char* BsB = (char*)Bs;

    f32x4 acc[4][4];
#pragma unroll
    for (int i = 0; i < 4; i++)
#pragma unroll
        for (int j = 0; j < 4; j++) acc[i][j] = (f32x4){0.f, 0.f, 0.f, 0.f};

    for (int k0 = 0; k0 < K; k0 += 32) {
        async16(AsB + t * 16,        a0 + k0);
        async16(AsB + 4096 + t * 16, a1 + k0);
        async16(BsB + t * 16,        b0 + k0);
        async16(BsB + 4096 + t * 16, b1 + k0);
        __syncthreads();
        bf16x8 af[4], bfr[4];
#pragma unroll
        for (int i = 0; i < 4; i++)
            af[i] = *(const bf16x8*)(AsB + (wm * 64 + i * 16 + lr) * 64 + lq * 16);
#pragma unroll
        for (int j = 0; j < 4; j++)
            bfr[j] = *(const bf16x8*)(BsB + (wn * 64 + j * 16 + lr) * 64 + lq * 16);
#pragma unroll
        for (int i = 0; i < 4; i++)
#pragma unroll
            for (int j = 0; j < 4; j++)
                acc[i][j] = __builtin_amdgcn_mfma_f32_16x16x32_bf16(af[i], bfr[j], acc[i][j], 0, 0, 0);
        __syncthreads();
    }

#pragma unroll
    for (int i = 0; i < 4; i++) {
        int rowb = m0 + wm * 64 + i * 16 + lq * 4;
#pragma unroll
        for (int j = 0; j < 4; j++) {
            int col = n0 + wn * 64 + j * 16 + lr;
            float bs = bias[col];
#pragma unroll
            for (int r = 0; r < 4; r++) {
                int rr = rowb + r;
                float val = acc[i][j][r] + bs;
                if (EPI == EPI_F32RES) {
                    Cf[(size_t)rr * N + col] = val + res[(size_t)rr * N + col];
                } else if (EPI == EPI_GELU) {
                    val = 0.5f * val * (1.f + erff(val * 0.70710678118654752f));
                    Cb[(size_t)rr * N + col] = f2bf(val);
                } else { // QKV scatter
                    int comp = col >> 10, cw = col & 1023;
                    int h = cw >> 6, d = cw & 63;
                    int bb = rr >> 11, ts = rr & 2047;
                    int bh = bb * NH + h;
                    u16 bv = f2bf(val);
                    if (comp == 0)      qb[((size_t)bh * SEQ + ts) * HDIM + d] = bv;
                    else if (comp == 1) kb[((size_t)bh * SEQ + ts) * HDIM + d] = bv;
                    else                vb[((size_t)bh * HDIM + d) * SEQ + ts] = bv;
                }
            }
        }
    }
}

// ---------------- flash attention, bf16 MFMA, 64 q-rows x 64 k-tiles ------------
// qb/kb: [bh][seq][64] bf16; vb: [bh][64][seq] bf16 (transposed); ctx: [tok][1024]
__global__ __launch_bounds__(256) void attn_mfma(const u16* __restrict__ qb,
                                                 const u16* __restrict__ kb,
                                                 const u16* __restrict__ vb,
                                                 u16* __restrict__ ctx)
{
    __shared__ __align__(16) u16 Qs[64 * 64];   // [q][d]   128B rows
    __shared__ __align__(16) u16 Ks[64 * 64];   // [key][d]
    __shared__ __align__(16) u16 Vt[64 * 64];   // [d][key]
    __shared__ __align__(16) u16 Ps[64 * 64];   // [q][key]
    int qt = blockIdx.x, bh = blockIdx.y;
    int bb = bh >> 4, h = bh & 15;
    int t = threadIdx.x, lane = t & 63, w = t >> 6;   // wave w owns q-rows [w*16, w*16+16)
    int lr = lane & 15, lq = lane >> 4;
    char* QsB = (char*)Qs; char* KsB = (char*)Ks;
    char* VtB = (char*)Vt; char* PsB = (char*)Ps;

    // stage Q tile (8KB contiguous)
    const char* qg = (const char*)(qb + ((size_t)bh * SEQ + qt * 64) * HDIM);
    async16(QsB + t * 16,        qg + t * 16);
    async16(QsB + 4096 + t * 16, qg + (size_t)4096 + t * 16);

    float mold[4] = {-INFINITY, -INFINITY, -INFINITY, -INFINITY};
    float lsum[4] = {0.f, 0.f, 0.f, 0.f};
    f32x4 o[4];
#pragma unroll
    for (int j = 0; j < 4; j++) o[j] = (f32x4){0.f, 0.f, 0.f, 0.f};

    for (int kt = 0; kt <= qt; kt++) {
        __syncthreads();   // prior iter done with Ks/Vt
        const char* kg = (const char*)(kb + ((size_t)bh * SEQ + kt * 64) * HDIM);
        async16(KsB + t * 16,        kg + t * 16);
        async16(KsB + 4096 + t * 16, kg + (size_t)4096 + t * 16);
        // Vt chunk c: d=c>>3, key8=c&7; global byte = d*SEQ*2 + kt*128 + key8*16
        const char* vg = (const char*)(vb + (size_t)bh * HDIM * SEQ) + (size_t)kt * 128;
        async16(VtB + t * 16,        vg + (size_t)(t >> 3) * (SEQ * 2) + (t & 7) * 16);
        async16(VtB + 4096 + t * 16, vg + (size_t)((t + 256) >> 3) * (SEQ * 2) + (t & 7) * 16);
        __syncthreads();

        // S = Q K^T (wave's 16 q-rows x 64 keys), fp32 acc
        bf16x8 aq0 = *(const bf16x8*)(QsB + (w * 16 + lr) * 128 + lq * 16);
        bf16x8 aq1 = *(const bf16x8*)(QsB + (w * 16 + lr) * 128 + 64 + lq * 16);
        float sv[4][4];
        bool diag = (kt == qt);
#pragma unroll
        for (int j = 0; j < 4; j++) {
            bf16x8 bk0 = *(const bf16x8*)(KsB + (j * 16 + lr) * 128 + lq * 16);
            bf16x8 bk1 = *(const bf16x8*)(KsB + (j * 16 + lr) * 128 + 64 + lq * 16);
            f32x4 z = (f32x4){0.f, 0.f, 0.f, 0.f};
            z = __builtin_amdgcn_mfma_f32_16x16x32_bf16(aq0, bk0, z, 0, 0, 0);
            z = __builtin_amdgcn_mfma_f32_16x16x32_bf16(aq1, bk1, z, 0, 0, 0);
#pragma unroll
            for (int r = 0; r < 4; r++) {
                float val = z[r] * 0.125f;   // 1/sqrt(64)
                if (diag && (j * 16 + lr > w * 16 + lq * 4 + r)) val = -INFINITY;
                sv[j][r] = val;
            }
        }
        // online softmax, fully in registers (rows live across lanes sharing lq)
        float mx[4];
#pragma unroll
        for (int r = 0; r < 4; r++)
            mx[r] = fmaxf(fmaxf(sv[0][r], sv[1][r]), fmaxf(sv[2][r], sv[3][r]));
#pragma unroll
        for (int msk = 1; msk < 16; msk <<= 1)
#pragma unroll
            for (int r = 0; r < 4; r++) mx[r] = fmaxf(mx[r], __shfl_xor(mx[r], msk, 64));
        float alpha[4], rs[4];
#pragma unroll
        for (int r = 0; r < 4; r++) {
            float mnew = fmaxf(mold[r], mx[r]);
            alpha[r] = __expf(mold[r] - mnew);
            mold[r] = mnew;
            rs[r] = 0.f;
        }
#pragma unroll
        for (int j = 0; j < 4; j++)
#pragma unroll
            for (int r = 0; r < 4; r++) {
                float p = __expf(sv[j][r] - mold[r]);
                sv[j][r] = p;
                rs[r] += p;
            }
#pragma unroll
        for (int msk = 1; msk < 16; msk <<= 1)
#pragma unroll
            for (int r = 0; r < 4; r++) rs[r] += __shfl_xor(rs[r], msk, 64);
#pragma unroll
        for (int r = 0; r < 4; r++) lsum[r] = lsum[r] * alpha[r] + rs[r];
#pragma unroll
        for (int j = 0; j < 4; j++)
#pragma unroll
            for (int r = 0; r < 4; r++) o[j][r] *= alpha[r];

        // P -> LDS (C-layout regs -> A-operand layout via round-trip)
        u16* PsU = (u16*)Ps;
#pragma unroll
        for (int j = 0; j < 4; j++)
#pragma unroll
            for (int r = 0; r < 4; r++)
                PsU[(w * 16 + lq * 4 + r) * 64 + j * 16 + lr] = f2bf(sv[j][r]);
        __syncthreads();

        // O += P V  (A = P rows, B = Vt)
        bf16x8 ap0 = *(const bf16x8*)(PsB + (w * 16 + lr) * 128 + lq * 16);
        bf16x8 ap1 = *(const bf16x8*)(PsB + (w * 16 + lr) * 128 + 64 + lq * 16);
#pragma unroll
        for (int dj = 0; dj < 4; dj++) {
            bf16x8 bv0 = *(const bf16x8*)(VtB + (dj * 16 + lr) * 128 + lq * 16);
            bf16x8 bv1 = *(const bf16x8*)(VtB + (dj * 16 + lr) * 128 + 64 + lq * 16);
            o[dj] = __builtin_amdgcn_mfma_f32_16x16x32_bf16(ap0, bv0, o[dj], 0, 0, 0);
            o[dj] = __builtin_amdgcn_mfma_f32_16x16x32_bf16(ap1, bv1, o[dj], 0, 0, 0);
        }
    }

#pragma unroll
    for (int r = 0; r < 4; r++) {
        float inv = 1.f / lsum[r];
        int tok = qt * 64 + w * 16 + lq * 4 + r;
        size_t base = ((size_t)bb * SEQ + tok) * TD + h * HDIM;
#pragma unroll
        for (int dj = 0; dj < 4; dj++)
            ctx[base + dj * 16 + lr] = f2bf(o[dj][r] * inv);
    }
}

extern "C" void kernel_launch(void* const* d_in, const int* in_sizes, int n_in,
                              void* d_out, int out_size, void* d_ws, size_t ws_size,
                              hipStream_t stream)
{
    const float* x    = (const float*)d_in[0];
    const float* g1   = (const float*)d_in[1];
    const float* b1   = (const float*)d_in[2];
    const float* Wqkv = (const float*)d_in[3];
    const float* bqkv = (const float*)d_in[4];
    const float* Wo   = (const float*)d_in[5];
    const float* bo   = (const float*)d_in[6];
    const float* g2   = (const float*)d_in[7];
    const float* b2   = (const float*)d_in[8];
    const float* W1   = (const float*)d_in[9];
    const float* b1f  = (const float*)d_in[10];
    const float* W2   = (const float*)d_in[11];
    const float* b2f  = (const float*)d_in[12];
    float* out = (float*)d_out;

    char* ws = (char*)d_ws;
    const size_t MB = 1ull << 20;
    u16* wqkvT = (u16*)(ws + 0 * MB);    // 6 MB  [3072][1024]
    u16* woT   = (u16*)(ws + 6 * MB);    // 2 MB  [1024][1024]
    u16* w1T   = (u16*)(ws + 8 * MB);    // 8 MB  [4096][1024]
    u16* w2T   = (u16*)(ws + 16 * MB);   // 8 MB  [1024][4096]
    u16* qbuf  = (u16*)(ws + 24 * MB);   // 8 MB  [32][2048][64]
    u16* kbuf  = (u16*)(ws + 32 * MB);   // 8 MB
    u16* vbuf  = (u16*)(ws + 40 * MB);   // 8 MB  [32][64][2048]
    u16* hbuf  = (u16*)(ws + 48 * MB);   // 8 MB  h then hh
    u16* ctx   = (u16*)(ws + 56 * MB);   // 8 MB
    float* x2  = (float*)(ws + 64 * MB); // 16 MB
    u16* ff1   = (u16*)(ws + 80 * MB);   // 32 MB  -> 112 MB total

    // weight transposes (fp32 -> bf16 [N][K])
    wconv_t<<<dim3(48, 16), 256, 0, stream>>>(Wqkv, wqkvT, TD, 3 * TD);
    wconv_t<<<dim3(16, 16), 256, 0, stream>>>(Wo,   woT,   TD, TD);
    wconv_t<<<dim3(64, 16), 256, 0, stream>>>(W1,   w1T,   TD, FFD);
    wconv_t<<<dim3(16, 64), 256, 0, stream>>>(W2,   w2T,   FFD, TD);

    // h = LN(x)
    ln_bf16<<<NROWS, 256, 0, stream>>>(x, g1, b1, hbuf);
    // qkv = h @ Wqkv + bqkv  -> scatter to qbuf/kbuf/vbuf(T)
    gemm_mfma<EPI_QKV><<<dim3(3 * TD / 128, NROWS / 128), 256, 0, stream>>>(
        NROWS, 3 * TD, TD, hbuf, wqkvT, bqkv, nullptr, nullptr, nullptr, qbuf, kbuf, vbuf);
    // ctx = causal_attention(q,k,v)
    attn_mfma<<<dim3(SEQ / 64, NB * NH), 256, 0, stream>>>(qbuf, kbuf, vbuf, ctx);
    // x2 = x + ctx @ Wo + bo
    gemm_mfma<EPI_F32RES><<<dim3(TD / 128, NROWS / 128), 256, 0, stream>>>(
        NROWS, TD, TD, ctx, woT, bo, x, x2, nullptr, nullptr, nullptr, nullptr);
    // hh = LN(x2)
    ln_bf16<<<NROWS, 256, 0, stream>>>(x2, g2, b2, hbuf);
    // ff1 = gelu(hh @ W1 + b1f)
    gemm_mfma<EPI_GELU><<<dim3(FFD / 128, NROWS / 128), 256, 0, stream>>>(
        NROWS, FFD, TD, hbuf, w1T, b1f, nullptr, nullptr, ff1, nullptr, nullptr, nullptr);
    // out = x2 + ff1 @ W2 + b2f
    gemm_mfma<EPI_F32RES><<<dim3(TD / 128, NROWS / 128), 256, 0, stream>>>(
        NROWS, TD, FFD, ff1, w2T, b2f, x2, out, nullptr, nullptr, nullptr, nullptr);
}

// Round 4
// 417.832 us; speedup vs baseline: 5.1707x; 1.2706x over previous
//
#include <hip/hip_runtime.h>
#include <math.h>

#define TD 1024      // model dim
#define NH 16        // heads
#define HDIM 64      // head dim
#define SEQ 2048     // seq len
#define NB 2         // batch
#define NROWS 4096   // NB*SEQ
#define FFD 4096     // ffn dim

// 1/sqrt(64) * log2(e): softmax computed in exp2 domain; folded into Q at QKV epilogue
#define QSCALE 0.18033688011112042f

typedef unsigned short u16;
typedef __attribute__((ext_vector_type(8))) short bf16x8;   // 8 bf16 = 4 VGPR
typedef __attribute__((ext_vector_type(4))) float f32x4;    // MFMA acc

__device__ __forceinline__ u16 f2bf(float f) {
    union { float f; unsigned u; } v; v.f = f;
    return (u16)((v.u + 0x7FFFu + ((v.u >> 16) & 1u)) >> 16);
}

// async global->LDS, 16B per lane. LDS dest must be wave-uniform base + lane*16.
__device__ __forceinline__ void async16(void* lds, const void* g) {
    __builtin_amdgcn_global_load_lds(
        (const __attribute__((address_space(1))) unsigned*)g,
        (__attribute__((address_space(3))) unsigned*)lds, 16, 0, 0);
}

// ---------------- LayerNorm -> bf16 out: one block per row of 1024 -------------
__global__ __launch_bounds__(256) void ln_bf16(const float* __restrict__ x,
                                               const float* __restrict__ g,
                                               const float* __restrict__ b,
                                               u16* __restrict__ out)
{
    int row = blockIdx.x;
    const float* xr = x + (size_t)row * TD;
    u16* outr = out + (size_t)row * TD;
    int t = threadIdx.x;
    float v[4];
    float s = 0.f, ss = 0.f;
#pragma unroll
    for (int i = 0; i < 4; i++) {
        v[i] = xr[t + 256 * i];
        s += v[i];
        ss += v[i] * v[i];
    }
#pragma unroll
    for (int o = 32; o > 0; o >>= 1) {
        s  += __shfl_down(s, o);
        ss += __shfl_down(ss, o);
    }
    __shared__ float sm[4], sm2[4];
    int wave = t >> 6, lane = t & 63;
    if (lane == 0) { sm[wave] = s; sm2[wave] = ss; }
    __syncthreads();
    s  = sm[0] + sm[1] + sm[2] + sm[3];
    ss = sm2[0] + sm2[1] + sm2[2] + sm2[3];
    float mu  = s * (1.f / TD);
    float var = ss * (1.f / TD) - mu * mu;
    float rstd = rsqrtf(var + 1e-5f);
#pragma unroll
    for (int i = 0; i < 4; i++) {
        int c = t + 256 * i;
        outr[c] = f2bf((v[i] - mu) * rstd * g[c] + b[c]);
    }
}

// ---------------- weight convert+transpose: W[K][N] fp32 -> Wt[N][K] bf16 ------
__global__ __launch_bounds__(256) void wconv_t(const float* __restrict__ W,
                                               u16* __restrict__ Wt, int K, int N)
{
    __shared__ u16 tile[64][65];
    int n0 = blockIdx.x * 64, k0 = blockIdx.y * 64;
    int t = threadIdx.x, c = t & 63, rq = t >> 6;
#pragma unroll
    for (int i = 0; i < 16; i++) {
        int r = rq * 16 + i;
        tile[r][c] = f2bf(W[(size_t)(k0 + r) * N + n0 + c]);
    }
    __syncthreads();
#pragma unroll
    for (int i = 0; i < 16; i++) {
        int r = rq * 16 + i;
        Wt[(size_t)(n0 + r) * K + k0 + c] = tile[c][r];
    }
}

// ---------------- bf16 MFMA GEMM, 128x128 tile, BK=32 --------------------------
// C[M,N] = A[M,K] @ Bt[N,K]^T + bias, with epilogues.
#define EPI_QKV 0
#define EPI_F32RES 1
#define EPI_GELU 2

template<int EPI>
__global__ __launch_bounds__(256) void gemm_mfma(int M, int N, int K,
    const u16* __restrict__ A, const u16* __restrict__ Bt,
    const float* __restrict__ bias, const float* __restrict__ res,
    float* __restrict__ Cf, u16* __restrict__ Cb,
    u16* __restrict__ qb, u16* __restrict__ kb, u16* __restrict__ vb)
{
    __shared__ __align__(16) u16 As[128 * 32];   // [m][k] row-major, 64B rows
    __shared__ __align__(16) u16 Bs[128 * 32];   // [n][k] row-major
    int t = threadIdx.x;
    int lane = t & 63, w = t >> 6;
    int wm = w >> 1, wn = w & 1;          // 2x2 wave grid, each wave 64x64
    int lr = lane & 15, lq = lane >> 4;
    int m0 = blockIdx.y * 128, n0 = blockIdx.x * 128;

    const u16* a0 = A + (size_t)(m0 + (t >> 2)) * K + (t & 3) * 8;
    const u16* a1 = a0 + (size_t)64 * K;
    const u16* b0 = Bt + (size_t)(n0 + (t >> 2)) * K + (t & 3) * 8;
    const u16* b1 = b0 + (size_t)64 * K;
    char* AsB = (char*)As;
    char* BsB = (char*)Bs;

    f32x4 acc[4][4];
#pragma unroll
    for (int i = 0; i < 4; i++)
#pragma unroll
        for (int j = 0; j < 4; j++) acc[i][j] = (f32x4){0.f, 0.f, 0.f, 0.f};

    for (int k0 = 0; k0 < K; k0 += 32) {
        async16(AsB + t * 16,        a0 + k0);
        async16(AsB + 4096 + t * 16, a1 + k0);
        async16(BsB + t * 16,        b0 + k0);
        async16(BsB + 4096 + t * 16, b1 + k0);
        __syncthreads();
        bf16x8 af[4], bfr[4];
#pragma unroll
        for (int i = 0; i < 4; i++)
            af[i] = *(const bf16x8*)(AsB + (wm * 64 + i * 16 + lr) * 64 + lq * 16);
#pragma unroll
        for (int j = 0; j < 4; j++)
            bfr[j] = *(const bf16x8*)(BsB + (wn * 64 + j * 16 + lr) * 64 + lq * 16);
#pragma unroll
        for (int i = 0; i < 4; i++)
#pragma unroll
            for (int j = 0; j < 4; j++)
                acc[i][j] = __builtin_amdgcn_mfma_f32_16x16x32_bf16(af[i], bfr[j], acc[i][j], 0, 0, 0);
        __syncthreads();
    }

#pragma unroll
    for (int i = 0; i < 4; i++) {
        int rowb = m0 + wm * 64 + i * 16 + lq * 4;
#pragma unroll
        for (int j = 0; j < 4; j++) {
            int col = n0 + wn * 64 + j * 16 + lr;
            float bs = bias[col];
            float vals[4];
#pragma unroll
            for (int r = 0; r < 4; r++) vals[r] = acc[i][j][r] + bs;
            if (EPI == EPI_F32RES) {
#pragma unroll
                for (int r = 0; r < 4; r++) {
                    int rr = rowb + r;
                    Cf[(size_t)rr * N + col] = vals[r] + res[(size_t)rr * N + col];
                }
            } else if (EPI == EPI_GELU) {
#pragma unroll
                for (int r = 0; r < 4; r++) {
                    float v = vals[r];
                    v = 0.5f * v * (1.f + erff(v * 0.70710678118654752f));
                    Cb[(size_t)(rowb + r) * N + col] = f2bf(v);
                }
            } else { // QKV scatter: Q/K [bh][seq][64] (Q pre-scaled), V [bh][64][seq]
                int comp = col >> 10, cw = col & 1023;
                int h = cw >> 6, d = cw & 63;
                int bb0 = rowb >> 11, ts = rowb & 2047;   // rowb%4==0: no batch crossing
                int bh = bb0 * NH + h;
                if (comp == 0) {
#pragma unroll
                    for (int r = 0; r < 4; r++)
                        qb[((size_t)bh * SEQ + ts + r) * HDIM + d] = f2bf(vals[r] * QSCALE);
                } else if (comp == 1) {
#pragma unroll
                    for (int r = 0; r < 4; r++)
                        kb[((size_t)bh * SEQ + ts + r) * HDIM + d] = f2bf(vals[r]);
                } else {
                    ushort4 pk;
                    pk.x = f2bf(vals[0]); pk.y = f2bf(vals[1]);
                    pk.z = f2bf(vals[2]); pk.w = f2bf(vals[3]);
                    *(ushort4*)&vb[((size_t)bh * HDIM + d) * SEQ + ts] = pk;
                }
            }
        }
    }
}

// ---------------- flash attention v2: S^T orientation, swizzled LDS, dbuf ------
// qb/kb: [bh][seq][64] bf16 (q pre-scaled by QSCALE); vb: [bh][64][seq] bf16
// Each block: q-tile pair (31-bx, bx) -> 33 k-tile iterations, perfectly balanced.
// LDS 40KB: QP (Q tile, reused as P buffer) + K dbuf + V dbuf, all XOR-swizzled:
//   chunk g (16B) of row r lives at byte r*128 + ((g ^ (r&7))*16).
__global__ __launch_bounds__(256, 4) void attn_mfma(const u16* __restrict__ qb,
                                                    const u16* __restrict__ kb,
                                                    const u16* __restrict__ vb,
                                                    u16* __restrict__ ctx)
{
    __shared__ __align__(16) char smem[40960];
    char* QP = smem;                        // 8KB Q tile / P buffer (wave-private rows)
    int bh = blockIdx.y, bb = bh >> 4, h = bh & 15;
    int t = threadIdx.x, lane = t & 63, w = t >> 6;
    int lr = lane & 15, lq = lane >> 4;
    int sw = (lr & 7) * 16;                 // read-side swizzle
    int cA = (lq * 16) ^ sw;                // chunk lq   (k-half 0)
    int cB = (64 | (lq * 16)) ^ sw;         // chunk 4+lq (k-half 1)
    // staging: thread covers LDS chunks t and t+256; swizzled global source
    int c0 = t,        r0 = c0 >> 3, g0 = (c0 & 7) ^ (r0 & 7);
    int c1 = t + 256,  r1 = c1 >> 3, g1 = (c1 & 7) ^ (r1 & 7);
    size_t off0  = (size_t)r0 * 128  + g0 * 16;   // Q/K tiles: 128B per row
    size_t off1  = (size_t)r1 * 128  + g1 * 16;
    size_t voff0 = (size_t)r0 * 4096 + g0 * 16;   // V: row=d, global stride 4096B
    size_t voff1 = (size_t)r1 * 4096 + g1 * 16;

    const char* qg_base = (const char*)qb + (size_t)bh * SEQ * 128;
    const char* kg_base = (const char*)kb + (size_t)bh * SEQ * 128;
    const char* vg_base = (const char*)vb + (size_t)bh * 64 * 4096;

    for (int pass = 0; pass < 2; ++pass) {
        int qt = pass ? blockIdx.x : (31 - blockIdx.x);
        if (pass) __syncthreads();          // QP/K0/V0 free before re-staging
        const char* qg = qg_base + (size_t)qt * 8192;
        async16(QP + c0 * 16, qg + off0);
        async16(QP + c1 * 16, qg + off1);
        async16(smem + 8192 + c0 * 16, kg_base + off0);
        async16(smem + 8192 + c1 * 16, kg_base + off1);
        async16(smem + 24576 + c0 * 16, vg_base + voff0);
        async16(smem + 24576 + c1 * 16, vg_base + voff1);

        float mold = -INFINITY, lsum = 0.f;
        f32x4 o[4];
#pragma unroll
        for (int dj = 0; dj < 4; dj++) o[dj] = (f32x4){0.f, 0.f, 0.f, 0.f};
        bf16x8 bq0, bq1;

        for (int kt = 0; kt <= qt; ++kt) {
            int cur = kt & 1;
            __syncthreads();                // tile kt ready; other buf free
            if (kt < qt) {                  // prefetch kt+1 (drained at next barrier)
                const char* kgn = kg_base + (size_t)(kt + 1) * 8192;
                const char* vgn = vg_base + (size_t)(kt + 1) * 128;
                char* Kn = smem + 8192  + (1 - cur) * 8192;
                char* Vn = smem + 24576 + (1 - cur) * 8192;
                async16(Kn + c0 * 16, kgn + off0);
                async16(Kn + c1 * 16, kgn + off1);
                async16(Vn + c0 * 16, vgn + voff0);
                async16(Vn + c1 * 16, vgn + voff1);
            }
            if (kt == 0) {                  // Q frags -> regs (QP then reused as P)
                const char* qr = QP + (w * 16 + lr) * 128;
                bq0 = *(const bf16x8*)(qr + cA);
                bq1 = *(const bf16x8*)(qr + cB);
            }
            const char* Kc = smem + 8192  + cur * 8192;
            const char* Vc = smem + 24576 + cur * 8192;

            // S^T = K Q^T : lane holds keys j*16+lq*4+r (rows), q = w*16+lr (col)
            float sv[4][4];
            bool diag = (kt == qt);
#pragma unroll
            for (int j = 0; j < 4; ++j) {
                const char* kr = Kc + (j * 16 + lr) * 128;
                bf16x8 ak0 = *(const bf16x8*)(kr + cA);
                bf16x8 ak1 = *(const bf16x8*)(kr + cB);
                f32x4 z = (f32x4){0.f, 0.f, 0.f, 0.f};
                z = __builtin_amdgcn_mfma_f32_16x16x32_bf16(ak0, bq0, z, 0, 0, 0);
                z = __builtin_amdgcn_mfma_f32_16x16x32_bf16(ak1, bq1, z, 0, 0, 0);
#pragma unroll
                for (int r = 0; r < 4; r++) {
                    float xv = z[r];
                    if (diag && (j * 16 + lq * 4 + r > w * 16 + lr)) xv = -INFINITY;
                    sv[j][r] = xv;
                }
            }
            // online softmax in exp2 domain; one q per lane
            float mx = sv[0][0];
#pragma unroll
            for (int j = 0; j < 4; j++)
#pragma unroll
                for (int r = 0; r < 4; r++) mx = fmaxf(mx, sv[j][r]);
            mx = fmaxf(mx, __shfl_xor(mx, 16));
            mx = fmaxf(mx, __shfl_xor(mx, 32));
            float mnew = fmaxf(mold, mx);
            float alpha = exp2f(mold - mnew);
            float rs = 0.f;
            unsigned pk[4][2];
#pragma unroll
            for (int j = 0; j < 4; j++)
#pragma unroll
                for (int hh = 0; hh < 2; hh++) {
                    float p0 = exp2f(sv[j][2 * hh]     - mnew);
                    float p1 = exp2f(sv[j][2 * hh + 1] - mnew);
                    rs += p0 + p1;
                    pk[j][hh] = (unsigned)f2bf(p0) | ((unsigned)f2bf(p1) << 16);
                }
            rs += __shfl_xor(rs, 16);
            rs += __shfl_xor(rs, 32);
            lsum = lsum * alpha + rs;
            mold = mnew;
#pragma unroll
            for (int dj = 0; dj < 4; dj++)
#pragma unroll
                for (int r = 0; r < 4; r++) o[dj][r] *= alpha;

            // P^T -> LDS (wave-private rows; no barrier): row q=w*16+lr, b64 writes
            {
                char* pw = QP + (w * 16 + lr) * 128 + (lq & 1) * 8;
#pragma unroll
                for (int j = 0; j < 4; j++) {
                    int pos = ((j * 2 + (lq >> 1)) * 16) ^ sw;
                    uint2 u; u.x = pk[j][0]; u.y = pk[j][1];
                    *(uint2*)(pw + pos) = u;
                }
            }
            asm volatile("s_waitcnt lgkmcnt(0)" ::: "memory");
            const char* pr = QP + (w * 16 + lr) * 128;
            bf16x8 bp0 = *(const bf16x8*)(pr + cA);
            bf16x8 bp1 = *(const bf16x8*)(pr + cB);
            // O^T += V^T P^T : rows d, cols q
#pragma unroll
            for (int dj = 0; dj < 4; ++dj) {
                const char* vr = Vc + (dj * 16 + lr) * 128;
                bf16x8 av0 = *(const bf16x8*)(vr + cA);
                bf16x8 av1 = *(const bf16x8*)(vr + cB);
                o[dj] = __builtin_amdgcn_mfma_f32_16x16x32_bf16(av0, bp0, o[dj], 0, 0, 0);
                o[dj] = __builtin_amdgcn_mfma_f32_16x16x32_bf16(av1, bp1, o[dj], 0, 0, 0);
            }
        }

        float inv = 1.f / lsum;
        int tok = qt * 64 + w * 16 + lr;
        u16* cp = ctx + ((size_t)(bb * SEQ) + tok) * TD + h * HDIM + lq * 4;
#pragma unroll
        for (int dj = 0; dj < 4; dj++) {
            ushort4 s4;
            s4.x = f2bf(o[dj][0] * inv); s4.y = f2bf(o[dj][1] * inv);
            s4.z = f2bf(o[dj][2] * inv); s4.w = f2bf(o[dj][3] * inv);
            *(ushort4*)(cp + dj * 16) = s4;
        }
    }
}

extern "C" void kernel_launch(void* const* d_in, const int* in_sizes, int n_in,
                              void* d_out, int out_size, void* d_ws, size_t ws_size,
                              hipStream_t stream)
{
    const float* x    = (const float*)d_in[0];
    const float* g1   = (const float*)d_in[1];
    const float* b1   = (const float*)d_in[2];
    const float* Wqkv = (const float*)d_in[3];
    const float* bqkv = (const float*)d_in[4];
    const float* Wo   = (const float*)d_in[5];
    const float* bo   = (const float*)d_in[6];
    const float* g2   = (const float*)d_in[7];
    const float* b2   = (const float*)d_in[8];
    const float* W1   = (const float*)d_in[9];
    const float* b1f  = (const float*)d_in[10];
    const float* W2   = (const float*)d_in[11];
    const float* b2f  = (const float*)d_in[12];
    float* out = (float*)d_out;

    char* ws = (char*)d_ws;
    const size_t MB = 1ull << 20;
    u16* wqkvT = (u16*)(ws + 0 * MB);    // 6 MB  [3072][1024]
    u16* woT   = (u16*)(ws + 6 * MB);    // 2 MB  [1024][1024]
    u16* w1T   = (u16*)(ws + 8 * MB);    // 8 MB  [4096][1024]
    u16* w2T   = (u16*)(ws + 16 * MB);   // 8 MB  [1024][4096]
    u16* qbuf  = (u16*)(ws + 24 * MB);   // 8 MB  [32][2048][64] (pre-scaled)
    u16* kbuf  = (u16*)(ws + 32 * MB);   // 8 MB
    u16* vbuf  = (u16*)(ws + 40 * MB);   // 8 MB  [32][64][2048]
    u16* hbuf  = (u16*)(ws + 48 * MB);   // 8 MB  h then hh
    u16* ctx   = (u16*)(ws + 56 * MB);   // 8 MB
    float* x2  = (float*)(ws + 64 * MB); // 16 MB
    u16* ff1   = (u16*)(ws + 80 * MB);   // 32 MB  -> 112 MB total

    wconv_t<<<dim3(48, 16), 256, 0, stream>>>(Wqkv, wqkvT, TD, 3 * TD);
    wconv_t<<<dim3(16, 16), 256, 0, stream>>>(Wo,   woT,   TD, TD);
    wconv_t<<<dim3(64, 16), 256, 0, stream>>>(W1,   w1T,   TD, FFD);
    wconv_t<<<dim3(16, 64), 256, 0, stream>>>(W2,   w2T,   FFD, TD);

    ln_bf16<<<NROWS, 256, 0, stream>>>(x, g1, b1, hbuf);
    gemm_mfma<EPI_QKV><<<dim3(3 * TD / 128, NROWS / 128), 256, 0, stream>>>(
        NROWS, 3 * TD, TD, hbuf, wqkvT, bqkv, nullptr, nullptr, nullptr, qbuf, kbuf, vbuf);
    attn_mfma<<<dim3(16, NB * NH), 256, 0, stream>>>(qbuf, kbuf, vbuf, ctx);
    gemm_mfma<EPI_F32RES><<<dim3(TD / 128, NROWS / 128), 256, 0, stream>>>(
        NROWS, TD, TD, ctx, woT, bo, x, x2, nullptr, nullptr, nullptr, nullptr);
    ln_bf16<<<NROWS, 256, 0, stream>>>(x2, g2, b2, hbuf);
    gemm_mfma<EPI_GELU><<<dim3(FFD / 128, NROWS / 128), 256, 0, stream>>>(
        NROWS, FFD, TD, hbuf, w1T, b1f, nullptr, nullptr, ff1, nullptr, nullptr, nullptr);
    gemm_mfma<EPI_F32RES><<<dim3(TD / 128, NROWS / 128), 256, 0, stream>>>(
        NROWS, TD, FFD, ff1, w2T, b2f, x2, out, nullptr, nullptr, nullptr, nullptr);
}

// Round 5
// 388.926 us; speedup vs baseline: 5.5550x; 1.0743x over previous
//
#include <hip/hip_runtime.h>
#include <math.h>

#define TD 1024      // model dim
#define NH 16        // heads
#define HDIM 64      // head dim
#define SEQ 2048     // seq len
#define NB 2         // batch
#define NROWS 4096   // NB*SEQ
#define FFD 4096     // ffn dim

// 1/sqrt(64) * log2(e): softmax computed in exp2 domain; folded into Q at QKV epilogue
#define QSCALE 0.18033688011112042f

typedef unsigned short u16;
typedef __attribute__((ext_vector_type(8))) short bf16x8;   // 8 bf16 = 4 VGPR
typedef __attribute__((ext_vector_type(4))) float f32x4;    // MFMA acc

__device__ __forceinline__ u16 f2bf(float f) {
    union { float f; unsigned u; } v; v.f = f;
    return (u16)((v.u + 0x7FFFu + ((v.u >> 16) & 1u)) >> 16);
}

// async global->LDS, 16B per lane. LDS dest must be wave-uniform base + lane*16.
__device__ __forceinline__ void async16(void* lds, const void* g) {
    __builtin_amdgcn_global_load_lds(
        (const __attribute__((address_space(1))) unsigned*)g,
        (__attribute__((address_space(3))) unsigned*)lds, 16, 0, 0);
}

// ---------------- LayerNorm -> bf16 out: one block per row of 1024 -------------
__global__ __launch_bounds__(256) void ln_bf16(const float* __restrict__ x,
                                               const float* __restrict__ g,
                                               const float* __restrict__ b,
                                               u16* __restrict__ out)
{
    int row = blockIdx.x;
    const float* xr = x + (size_t)row * TD;
    u16* outr = out + (size_t)row * TD;
    int t = threadIdx.x;
    float v[4];
    float s = 0.f, ss = 0.f;
#pragma unroll
    for (int i = 0; i < 4; i++) {
        v[i] = xr[t + 256 * i];
        s += v[i];
        ss += v[i] * v[i];
    }
#pragma unroll
    for (int o = 32; o > 0; o >>= 1) {
        s  += __shfl_down(s, o);
        ss += __shfl_down(ss, o);
    }
    __shared__ float sm[4], sm2[4];
    int wave = t >> 6, lane = t & 63;
    if (lane == 0) { sm[wave] = s; sm2[wave] = ss; }
    __syncthreads();
    s  = sm[0] + sm[1] + sm[2] + sm[3];
    ss = sm2[0] + sm2[1] + sm2[2] + sm2[3];
    float mu  = s * (1.f / TD);
    float var = ss * (1.f / TD) - mu * mu;
    float rstd = rsqrtf(var + 1e-5f);
#pragma unroll
    for (int i = 0; i < 4; i++) {
        int c = t + 256 * i;
        outr[c] = f2bf((v[i] - mu) * rstd * g[c] + b[c]);
    }
}

// ---------------- weight convert+transpose: W[K][N] fp32 -> Wt[N][K] bf16 ------
__global__ __launch_bounds__(256) void wconv_t(const float* __restrict__ W,
                                               u16* __restrict__ Wt, int K, int N)
{
    __shared__ u16 tile[64][65];
    int n0 = blockIdx.x * 64, k0 = blockIdx.y * 64;
    int t = threadIdx.x, c = t & 63, rq = t >> 6;
#pragma unroll
    for (int i = 0; i < 16; i++) {
        int r = rq * 16 + i;
        tile[r][c] = f2bf(W[(size_t)(k0 + r) * N + n0 + c]);
    }
    __syncthreads();
#pragma unroll
    for (int i = 0; i < 16; i++) {
        int r = rq * 16 + i;
        Wt[(size_t)(n0 + r) * K + k0 + c] = tile[c][r];
    }
}

// ---------------- bf16 MFMA GEMM, 128xTN tile, BK=32, swizzled LDS -------------
// C[M,N] = A[M,K] @ Bt[N,K]^T + bias, with epilogues.
// LDS layout: chunk (16B) g of tile-row r stored at slot g ^ ((r>>1)&3) within
// the row's 64B. Frag-read start banks: 16*(lr&1) + 4*(lq^((lr>>1)&3)) -> all 8
// four-bank groups covered, 2-way aliasing only (free).
#define EPI_QKV 0
#define EPI_F32RES 1
#define EPI_GELU 2

template<int EPI, int TN>
__global__ __launch_bounds__(256) void gemm_mfma(int M, int N, int K,
    const u16* __restrict__ A, const u16* __restrict__ Bt,
    const float* __restrict__ bias, const float* __restrict__ res,
    float* __restrict__ Cf, u16* __restrict__ Cb,
    u16* __restrict__ qb, u16* __restrict__ kb, u16* __restrict__ vb)
{
    constexpr int WN = TN / 2;        // per-wave N extent (2 waves along N)
    constexpr int NJ = WN / 16;       // B frags per wave
    __shared__ __align__(16) u16 As[128 * 32];
    __shared__ __align__(16) u16 Bs[TN * 32];
    int t = threadIdx.x;
    int lane = t & 63, w = t >> 6;
    int wm = w >> 1, wn = w & 1;      // 2x2 wave grid: wave = 64(M) x WN(N)
    int lr = lane & 15, lq = lane >> 4;
    int m0 = blockIdx.y * 128, n0 = blockIdx.x * TN;
    int swc = ((lq ^ ((lr >> 1) & 3)) * 16);   // swizzled frag-read chunk offset

    // staging: thread t covers LDS chunk t (and t+256 where applicable);
    // LDS chunk c = row (c>>2), slot (c&3) -> global k8 = (c&3) ^ ((row>>1)&3)
    int rs = t >> 2;
    int gs = ((t & 3) ^ ((rs >> 1) & 3)) * 8;
    const u16* a0 = A + (size_t)(m0 + rs) * K + gs;
    const u16* a1 = a0 + (size_t)64 * K;       // row rs+64: same swizzle (+64 even)
    const u16* b0 = Bt + (size_t)(n0 + rs) * K + gs;
    const u16* b1 = b0 + (size_t)64 * K;       // TN=128 only
    char* AsB = (char*)As;
    char* BsB = (char*)Bs;

    f32x4 acc[4][NJ];
#pragma unroll
    for (int i = 0; i < 4; i++)
#pragma unroll
        for (int j = 0; j < NJ; j++) acc[i][j] = (f32x4){0.f, 0.f, 0.f, 0.f};

    for (int k0 = 0; k0 < K; k0 += 32) {
        async16(AsB + t * 16,        a0 + k0);
        async16(AsB + 4096 + t * 16, a1 + k0);
        async16(BsB + t * 16,        b0 + k0);
        if (TN == 128) async16(BsB + 4096 + t * 16, b1 + k0);
        __syncthreads();
        bf16x8 af[4], bfr[NJ];
#pragma unroll
        for (int i = 0; i < 4; i++)
            af[i] = *(const bf16x8*)(AsB + (wm * 64 + i * 16 + lr) * 64 + swc);
#pragma unroll
        for (int j = 0; j < NJ; j++)
            bfr[j] = *(const bf16x8*)(BsB + (wn * WN + j * 16 + lr) * 64 + swc);
#pragma unroll
        for (int i = 0; i < 4; i++)
#pragma unroll
            for (int j = 0; j < NJ; j++)
                acc[i][j] = __builtin_amdgcn_mfma_f32_16x16x32_bf16(af[i], bfr[j], acc[i][j], 0, 0, 0);
        __syncthreads();
    }

#pragma unroll
    for (int i = 0; i < 4; i++) {
        int rowb = m0 + wm * 64 + i * 16 + lq * 4;
#pragma unroll
        for (int j = 0; j < NJ; j++) {
            int col = n0 + wn * WN + j * 16 + lr;
            float bs = bias[col];
            float vals[4];
#pragma unroll
            for (int r = 0; r < 4; r++) vals[r] = acc[i][j][r] + bs;
            if (EPI == EPI_F32RES) {
#pragma unroll
                for (int r = 0; r < 4; r++) {
                    int rr = rowb + r;
                    Cf[(size_t)rr * N + col] = vals[r] + res[(size_t)rr * N + col];
                }
            } else if (EPI == EPI_GELU) {
#pragma unroll
                for (int r = 0; r < 4; r++) {
                    float v = vals[r];
                    v = 0.5f * v * (1.f + erff(v * 0.70710678118654752f));
                    Cb[(size_t)(rowb + r) * N + col] = f2bf(v);
                }
            } else { // QKV scatter: Q/K [bh][seq][64] (Q pre-scaled), V [bh][64][seq]
                int comp = col >> 10, cw = col & 1023;
                int h = cw >> 6, d = cw & 63;
                int bb0 = rowb >> 11, ts = rowb & 2047;   // rowb%4==0: no batch crossing
                int bh = bb0 * NH + h;
                if (comp == 0) {
#pragma unroll
                    for (int r = 0; r < 4; r++)
                        qb[((size_t)bh * SEQ + ts + r) * HDIM + d] = f2bf(vals[r] * QSCALE);
                } else if (comp == 1) {
#pragma unroll
                    for (int r = 0; r < 4; r++)
                        kb[((size_t)bh * SEQ + ts + r) * HDIM + d] = f2bf(vals[r]);
                } else {
                    ushort4 pk;
                    pk.x = f2bf(vals[0]); pk.y = f2bf(vals[1]);
                    pk.z = f2bf(vals[2]); pk.w = f2bf(vals[3]);
                    *(ushort4*)&vb[((size_t)bh * HDIM + d) * SEQ + ts] = pk;
                }
            }
        }
    }
}

// ---------------- flash attention v2: S^T orientation, swizzled LDS, dbuf ------
// qb/kb: [bh][seq][64] bf16 (q pre-scaled by QSCALE); vb: [bh][64][seq] bf16
// Each block: q-tile pair (31-bx, bx) -> 33 k-tile iterations, perfectly balanced.
// LDS 40KB: QP (Q tile, reused as P buffer) + K dbuf + V dbuf, all XOR-swizzled:
//   chunk g (16B) of row r lives at byte r*128 + ((g ^ (r&7))*16).
__global__ __launch_bounds__(256, 4) void attn_mfma(const u16* __restrict__ qb,
                                                    const u16* __restrict__ kb,
                                                    const u16* __restrict__ vb,
                                                    u16* __restrict__ ctx)
{
    __shared__ __align__(16) char smem[40960];
    char* QP = smem;                        // 8KB Q tile / P buffer (wave-private rows)
    int bh = blockIdx.y, bb = bh >> 4, h = bh & 15;
    int t = threadIdx.x, lane = t & 63, w = t >> 6;
    int lr = lane & 15, lq = lane >> 4;
    int sw = (lr & 7) * 16;                 // read-side swizzle
    int cA = (lq * 16) ^ sw;                // chunk lq   (k-half 0)
    int cB = (64 | (lq * 16)) ^ sw;         // chunk 4+lq (k-half 1)
    // staging: thread covers LDS chunks t and t+256; swizzled global source
    int c0 = t,        r0 = c0 >> 3, g0 = (c0 & 7) ^ (r0 & 7);
    int c1 = t + 256,  r1 = c1 >> 3, g1 = (c1 & 7) ^ (r1 & 7);
    size_t off0  = (size_t)r0 * 128  + g0 * 16;   // Q/K tiles: 128B per row
    size_t off1  = (size_t)r1 * 128  + g1 * 16;
    size_t voff0 = (size_t)r0 * 4096 + g0 * 16;   // V: row=d, global stride 4096B
    size_t voff1 = (size_t)r1 * 4096 + g1 * 16;

    const char* qg_base = (const char*)qb + (size_t)bh * SEQ * 128;
    const char* kg_base = (const char*)kb + (size_t)bh * SEQ * 128;
    const char* vg_base = (const char*)vb + (size_t)bh * 64 * 4096;

    for (int pass = 0; pass < 2; ++pass) {
        int qt = pass ? blockIdx.x : (31 - blockIdx.x);
        if (pass) __syncthreads();          // QP/K0/V0 free before re-staging
        const char* qg = qg_base + (size_t)qt * 8192;
        async16(QP + c0 * 16, qg + off0);
        async16(QP + c1 * 16, qg + off1);
        async16(smem + 8192 + c0 * 16, kg_base + off0);
        async16(smem + 8192 + c1 * 16, kg_base + off1);
        async16(smem + 24576 + c0 * 16, vg_base + voff0);
        async16(smem + 24576 + c1 * 16, vg_base + voff1);

        float mold = -INFINITY, lsum = 0.f;
        f32x4 o[4];
#pragma unroll
        for (int dj = 0; dj < 4; dj++) o[dj] = (f32x4){0.f, 0.f, 0.f, 0.f};
        bf16x8 bq0, bq1;

        for (int kt = 0; kt <= qt; ++kt) {
            int cur = kt & 1;
            __syncthreads();                // tile kt ready; other buf free
            if (kt < qt) {                  // prefetch kt+1 (drained at next barrier)
                const char* kgn = kg_base + (size_t)(kt + 1) * 8192;
                const char* vgn = vg_base + (size_t)(kt + 1) * 128;
                char* Kn = smem + 8192  + (1 - cur) * 8192;
                char* Vn = smem + 24576 + (1 - cur) * 8192;
                async16(Kn + c0 * 16, kgn + off0);
                async16(Kn + c1 * 16, kgn + off1);
                async16(Vn + c0 * 16, vgn + voff0);
                async16(Vn + c1 * 16, vgn + voff1);
            }
            if (kt == 0) {                  // Q frags -> regs (QP then reused as P)
                const char* qr = QP + (w * 16 + lr) * 128;
                bq0 = *(const bf16x8*)(qr + cA);
                bq1 = *(const bf16x8*)(qr + cB);
            }
            const char* Kc = smem + 8192  + cur * 8192;
            const char* Vc = smem + 24576 + cur * 8192;

            // S^T = K Q^T : lane holds keys j*16+lq*4+r (rows), q = w*16+lr (col)
            float sv[4][4];
            bool diag = (kt == qt);
#pragma unroll
            for (int j = 0; j < 4; ++j) {
                const char* kr = Kc + (j * 16 + lr) * 128;
                bf16x8 ak0 = *(const bf16x8*)(kr + cA);
                bf16x8 ak1 = *(const bf16x8*)(kr + cB);
                f32x4 z = (f32x4){0.f, 0.f, 0.f, 0.f};
                z = __builtin_amdgcn_mfma_f32_16x16x32_bf16(ak0, bq0, z, 0, 0, 0);
                z = __builtin_amdgcn_mfma_f32_16x16x32_bf16(ak1, bq1, z, 0, 0, 0);
#pragma unroll
                for (int r = 0; r < 4; r++) {
                    float xv = z[r];
                    if (diag && (j * 16 + lq * 4 + r > w * 16 + lr)) xv = -INFINITY;
                    sv[j][r] = xv;
                }
            }
            // online softmax in exp2 domain; one q per lane
            float mx = sv[0][0];
#pragma unroll
            for (int j = 0; j < 4; j++)
#pragma unroll
                for (int r = 0; r < 4; r++) mx = fmaxf(mx, sv[j][r]);
            mx = fmaxf(mx, __shfl_xor(mx, 16));
            mx = fmaxf(mx, __shfl_xor(mx, 32));
            float mnew = fmaxf(mold, mx);
            float alpha = exp2f(mold - mnew);
            float rs = 0.f;
            unsigned pk[4][2];
#pragma unroll
            for (int j = 0; j < 4; j++)
#pragma unroll
                for (int hh = 0; hh < 2; hh++) {
                    float p0 = exp2f(sv[j][2 * hh]     - mnew);
                    float p1 = exp2f(sv[j][2 * hh + 1] - mnew);
                    rs += p0 + p1;
                    pk[j][hh] = (unsigned)f2bf(p0) | ((unsigned)f2bf(p1) << 16);
                }
            rs += __shfl_xor(rs, 16);
            rs += __shfl_xor(rs, 32);
            lsum = lsum * alpha + rs;
            mold = mnew;
#pragma unroll
            for (int dj = 0; dj < 4; dj++)
#pragma unroll
                for (int r = 0; r < 4; r++) o[dj][r] *= alpha;

            // P^T -> LDS (wave-private rows; no barrier): row q=w*16+lr, b64 writes
            {
                char* pw = QP + (w * 16 + lr) * 128 + (lq & 1) * 8;
#pragma unroll
                for (int j = 0; j < 4; j++) {
                    int pos = ((j * 2 + (lq >> 1)) * 16) ^ sw;
                    uint2 u; u.x = pk[j][0]; u.y = pk[j][1];
                    *(uint2*)(pw + pos) = u;
                }
            }
            asm volatile("s_waitcnt lgkmcnt(0)" ::: "memory");
            const char* pr = QP + (w * 16 + lr) * 128;
            bf16x8 bp0 = *(const bf16x8*)(pr + cA);
            bf16x8 bp1 = *(const bf16x8*)(pr + cB);
            // O^T += V^T P^T : rows d, cols q
#pragma unroll
            for (int dj = 0; dj < 4; ++dj) {
                const char* vr = Vc + (dj * 16 + lr) * 128;
                bf16x8 av0 = *(const bf16x8*)(vr + cA);
                bf16x8 av1 = *(const bf16x8*)(vr + cB);
                o[dj] = __builtin_amdgcn_mfma_f32_16x16x32_bf16(av0, bp0, o[dj], 0, 0, 0);
                o[dj] = __builtin_amdgcn_mfma_f32_16x16x32_bf16(av1, bp1, o[dj], 0, 0, 0);
            }
        }

        float inv = 1.f / lsum;
        int tok = qt * 64 + w * 16 + lr;
        u16* cp = ctx + ((size_t)(bb * SEQ) + tok) * TD + h * HDIM + lq * 4;
#pragma unroll
        for (int dj = 0; dj < 4; dj++) {
            ushort4 s4;
            s4.x = f2bf(o[dj][0] * inv); s4.y = f2bf(o[dj][1] * inv);
            s4.z = f2bf(o[dj][2] * inv); s4.w = f2bf(o[dj][3] * inv);
            *(ushort4*)(cp + dj * 16) = s4;
        }
    }
}

extern "C" void kernel_launch(void* const* d_in, const int* in_sizes, int n_in,
                              void* d_out, int out_size, void* d_ws, size_t ws_size,
                              hipStream_t stream)
{
    const float* x    = (const float*)d_in[0];
    const float* g1   = (const float*)d_in[1];
    const float* b1   = (const float*)d_in[2];
    const float* Wqkv = (const float*)d_in[3];
    const float* bqkv = (const float*)d_in[4];
    const float* Wo   = (const float*)d_in[5];
    const float* bo   = (const float*)d_in[6];
    const float* g2   = (const float*)d_in[7];
    const float* b2   = (const float*)d_in[8];
    const float* W1   = (const float*)d_in[9];
    const float* b1f  = (const float*)d_in[10];
    const float* W2   = (const float*)d_in[11];
    const float* b2f  = (const float*)d_in[12];
    float* out = (float*)d_out;

    char* ws = (char*)d_ws;
    const size_t MB = 1ull << 20;
    u16* wqkvT = (u16*)(ws + 0 * MB);    // 6 MB  [3072][1024]
    u16* woT   = (u16*)(ws + 6 * MB);    // 2 MB  [1024][1024]
    u16* w1T   = (u16*)(ws + 8 * MB);    // 8 MB  [4096][1024]
    u16* w2T   = (u16*)(ws + 16 * MB);   // 8 MB  [1024][4096]
    u16* qbuf  = (u16*)(ws + 24 * MB);   // 8 MB  [32][2048][64] (pre-scaled)
    u16* kbuf  = (u16*)(ws + 32 * MB);   // 8 MB
    u16* vbuf  = (u16*)(ws + 40 * MB);   // 8 MB  [32][64][2048]
    u16* hbuf  = (u16*)(ws + 48 * MB);   // 8 MB  h then hh
    u16* ctx   = (u16*)(ws + 56 * MB);   // 8 MB
    float* x2  = (float*)(ws + 64 * MB); // 16 MB
    u16* ff1   = (u16*)(ws + 80 * MB);   // 32 MB  -> 112 MB total

    wconv_t<<<dim3(48, 16), 256, 0, stream>>>(Wqkv, wqkvT, TD, 3 * TD);
    wconv_t<<<dim3(16, 16), 256, 0, stream>>>(Wo,   woT,   TD, TD);
    wconv_t<<<dim3(64, 16), 256, 0, stream>>>(W1,   w1T,   TD, FFD);
    wconv_t<<<dim3(16, 64), 256, 0, stream>>>(W2,   w2T,   FFD, TD);

    ln_bf16<<<NROWS, 256, 0, stream>>>(x, g1, b1, hbuf);
    gemm_mfma<EPI_QKV, 128><<<dim3(3 * TD / 128, NROWS / 128), 256, 0, stream>>>(
        NROWS, 3 * TD, TD, hbuf, wqkvT, bqkv, nullptr, nullptr, nullptr, qbuf, kbuf, vbuf);
    attn_mfma<<<dim3(16, NB * NH), 256, 0, stream>>>(qbuf, kbuf, vbuf, ctx);
    gemm_mfma<EPI_F32RES, 64><<<dim3(TD / 64, NROWS / 128), 256, 0, stream>>>(
        NROWS, TD, TD, ctx, woT, bo, x, x2, nullptr, nullptr, nullptr, nullptr);
    ln_bf16<<<NROWS, 256, 0, stream>>>(x2, g2, b2, hbuf);
    gemm_mfma<EPI_GELU, 128><<<dim3(FFD / 128, NROWS / 128), 256, 0, stream>>>(
        NROWS, FFD, TD, hbuf, w1T, b1f, nullptr, nullptr, ff1, nullptr, nullptr, nullptr);
    gemm_mfma<EPI_F32RES, 64><<<dim3(TD / 64, NROWS / 128), 256, 0, stream>>>(
        NROWS, TD, FFD, ff1, w2T, b2f, x2, out, nullptr, nullptr, nullptr, nullptr);
}

// Round 6
// 335.189 us; speedup vs baseline: 6.4456x; 1.1603x over previous
//
#include <hip/hip_runtime.h>
#include <math.h>

#define TD 1024      // model dim
#define NH 16        // heads
#define HDIM 64      // head dim
#define SEQ 2048     // seq len
#define NB 2         // batch
#define NROWS 4096   // NB*SEQ
#define FFD 4096     // ffn dim

// 1/sqrt(64) * log2(e): softmax computed in exp2 domain; folded into Q at QKV epilogue
#define QSCALE 0.18033688011112042f

typedef unsigned short u16;
typedef __attribute__((ext_vector_type(8))) short bf16x8;   // 8 bf16 = 4 VGPR
typedef __attribute__((ext_vector_type(4))) float f32x4;    // MFMA acc

__device__ __forceinline__ u16 f2bf(float f) {
    union { float f; unsigned u; } v; v.f = f;
    return (u16)((v.u + 0x7FFFu + ((v.u >> 16) & 1u)) >> 16);
}

// async global->LDS, 16B per lane. LDS dest must be wave-uniform base + lane*16.
__device__ __forceinline__ void async16(void* lds, const void* g) {
    __builtin_amdgcn_global_load_lds(
        (const __attribute__((address_space(1))) unsigned*)g,
        (__attribute__((address_space(3))) unsigned*)lds, 16, 0, 0);
}

// ---------------- LayerNorm -> bf16 out: one block per row of 1024 -------------
__global__ __launch_bounds__(256) void ln_bf16(const float* __restrict__ x,
                                               const float* __restrict__ g,
                                               const float* __restrict__ b,
                                               u16* __restrict__ out)
{
    int row = blockIdx.x;
    const float* xr = x + (size_t)row * TD;
    u16* outr = out + (size_t)row * TD;
    int t = threadIdx.x;
    float v[4];
    float s = 0.f, ss = 0.f;
#pragma unroll
    for (int i = 0; i < 4; i++) {
        v[i] = xr[t + 256 * i];
        s += v[i];
        ss += v[i] * v[i];
    }
#pragma unroll
    for (int o = 32; o > 0; o >>= 1) {
        s  += __shfl_down(s, o);
        ss += __shfl_down(ss, o);
    }
    __shared__ float sm[4], sm2[4];
    int wave = t >> 6, lane = t & 63;
    if (lane == 0) { sm[wave] = s; sm2[wave] = ss; }
    __syncthreads();
    s  = sm[0] + sm[1] + sm[2] + sm[3];
    ss = sm2[0] + sm2[1] + sm2[2] + sm2[3];
    float mu  = s * (1.f / TD);
    float var = ss * (1.f / TD) - mu * mu;
    float rstd = rsqrtf(var + 1e-5f);
#pragma unroll
    for (int i = 0; i < 4; i++) {
        int c = t + 256 * i;
        outr[c] = f2bf((v[i] - mu) * rstd * g[c] + b[c]);
    }
}

// ------- fused weight convert+transpose: all four W[K][N] fp32 -> Wt[N][K] bf16 -
__global__ __launch_bounds__(256) void wconv_all(
    const float* __restrict__ Wqkv, const float* __restrict__ Wo,
    const float* __restrict__ W1,   const float* __restrict__ W2,
    u16* __restrict__ wqkvT, u16* __restrict__ woT,
    u16* __restrict__ w1T,   u16* __restrict__ w2T)
{
    int blk = blockIdx.x;
    const float* W; u16* Wt; int K, N, local, nx;
    if (blk < 768)       { W = Wqkv; Wt = wqkvT; K = TD;  N = 3 * TD; local = blk;        nx = 48; }
    else if (blk < 1024) { W = Wo;   Wt = woT;   K = TD;  N = TD;     local = blk - 768;  nx = 16; }
    else if (blk < 2048) { W = W1;   Wt = w1T;   K = TD;  N = FFD;    local = blk - 1024; nx = 64; }
    else                 { W = W2;   Wt = w2T;   K = FFD; N = TD;     local = blk - 2048; nx = 16; }
    int n0 = (local % nx) * 64, k0 = (local / nx) * 64;
    __shared__ u16 tile[64][65];
    int t = threadIdx.x, c = t & 63, rq = t >> 6;
#pragma unroll
    for (int i = 0; i < 16; i++) {
        int r = rq * 16 + i;
        tile[r][c] = f2bf(W[(size_t)(k0 + r) * N + n0 + c]);
    }
    __syncthreads();
#pragma unroll
    for (int i = 0; i < 16; i++) {
        int r = rq * 16 + i;
        Wt[(size_t)(n0 + r) * K + k0 + c] = tile[c][r];
    }
}

// ---------------- bf16 MFMA GEMM: 128xTN tile, BK k-slab, dbuf LDS -------------
// C[M,N] = A[M,K] @ Bt[N,K]^T + bias, with epilogues.
// Pipeline: one barrier per K-step; prefetch of slab k+1 issued right AFTER the
// barrier that publishes slab k, so the vmcnt(0) drain at the next barrier waits
// on loads that had a full compute phase in flight (attn-style).
// LDS swizzle: within each 64B k-half of a row, 16B chunk g stored at slot
// g ^ ((row>>1)&3). Frag reads hit all 8 bank groups, 2-way only (free).
// XCD swizzle: tiles remapped so all N-tiles of an M-row land on one XCD's L2.
#define EPI_QKV 0
#define EPI_F32RES 1
#define EPI_GELU 2

template<int EPI, int TN, int BK>
__global__ __launch_bounds__(256) void gemm_mfma(int M, int N, int K,
    const u16* __restrict__ A, const u16* __restrict__ Bt,
    const float* __restrict__ bias, const float* __restrict__ res,
    float* __restrict__ Cf, u16* __restrict__ Cb,
    u16* __restrict__ qb, u16* __restrict__ kb, u16* __restrict__ vb)
{
    constexpr int WN  = TN / 2;               // per-wave N extent (2 waves along N)
    constexpr int NJ  = WN / 16;              // B frags per wave
    constexpr int KH  = BK / 32;              // 32-elem k-halves per slab
    constexpr int CPR = BK / 8;               // 16B chunks per tile-row
    constexpr int ACH = (128 * CPR) / 256;    // A chunks per thread
    constexpr int BCH = (TN  * CPR) / 256;    // B chunks per thread
    constexpr int ASZ = 128 * BK * 2;         // bytes per A buffer
    constexpr int BSZ = TN  * BK * 2;
    __shared__ __align__(16) char smem[2 * (ASZ + BSZ)];

    int t = threadIdx.x;
    int lane = t & 63, w = t >> 6;
    int wm = w >> 1, wn = w & 1;              // 2x2 wave grid: wave = 64(M) x WN(N)
    int lr = lane & 15, lq = lane >> 4;
    // XCD-aware tile remap (gridDim.y % 8 == 0 for all our launches)
    int gx = gridDim.x;
    int lin = blockIdx.x + gx * blockIdx.y;
    int li = lin >> 3;
    int qy = li / gx;
    int ty = (lin & 7) * (gridDim.y >> 3) + qy;
    int tx = li - qy * gx;
    int m0 = ty * 128, n0 = tx * TN;
    int swc = (lq ^ ((lr >> 1) & 3)) * 16;    // swizzled frag-read chunk offset

    // per-thread staging source offsets (elements); LDS chunk c = t + 256*i at byte c*16
    int aoff[ACH], boff[BCH];
#pragma unroll
    for (int i = 0; i < ACH; i++) {
        int c = t + 256 * i, r = c / CPR, ww = c % CPR;
        int g = (ww & ~3) | ((ww & 3) ^ ((r >> 1) & 3));
        aoff[i] = (m0 + r) * K + g * 8;
    }
#pragma unroll
    for (int i = 0; i < BCH; i++) {
        int c = t + 256 * i, r = c / CPR, ww = c % CPR;
        int g = (ww & ~3) | ((ww & 3) ^ ((r >> 1) & 3));
        boff[i] = (n0 + r) * K + g * 8;
    }

    f32x4 acc[4][NJ];
#pragma unroll
    for (int i = 0; i < 4; i++)
#pragma unroll
        for (int j = 0; j < NJ; j++) acc[i][j] = (f32x4){0.f, 0.f, 0.f, 0.f};

    // prologue: stage slab 0 into buffer 0
#pragma unroll
    for (int i = 0; i < ACH; i++)
        async16(smem + (t + 256 * i) * 16, A + aoff[i]);
#pragma unroll
    for (int i = 0; i < BCH; i++)
        async16(smem + 2 * ASZ + (t + 256 * i) * 16, Bt + boff[i]);

    int nk = K / BK;
    for (int kt = 0; kt < nk; kt++) {
        int cur = kt & 1;
        __syncthreads();                      // slab kt ready; other buffer free
        if (kt + 1 < nk) {                    // prefetch slab kt+1 (drains at next barrier)
            int kn = (kt + 1) * BK;
            char* An = smem + (1 - cur) * ASZ;
            char* Bn = smem + 2 * ASZ + (1 - cur) * BSZ;
#pragma unroll
            for (int i = 0; i < ACH; i++)
                async16(An + (t + 256 * i) * 16, A + aoff[i] + kn);
#pragma unroll
            for (int i = 0; i < BCH; i++)
                async16(Bn + (t + 256 * i) * 16, Bt + boff[i] + kn);
        }
        const char* Ac = smem + cur * ASZ;
        const char* Bc = smem + 2 * ASZ + cur * BSZ;
#pragma unroll
        for (int h = 0; h < KH; h++) {
            bf16x8 af[4], bfr[NJ];
#pragma unroll
            for (int i = 0; i < 4; i++)
                af[i] = *(const bf16x8*)(Ac + (wm * 64 + i * 16 + lr) * (2 * BK) + h * 64 + swc);
#pragma unroll
            for (int j = 0; j < NJ; j++)
                bfr[j] = *(const bf16x8*)(Bc + (wn * WN + j * 16 + lr) * (2 * BK) + h * 64 + swc);
#pragma unroll
            for (int i = 0; i < 4; i++)
#pragma unroll
                for (int j = 0; j < NJ; j++)
                    acc[i][j] = __builtin_amdgcn_mfma_f32_16x16x32_bf16(af[i], bfr[j], acc[i][j], 0, 0, 0);
        }
    }

#pragma unroll
    for (int i = 0; i < 4; i++) {
        int rowb = m0 + wm * 64 + i * 16 + lq * 4;
#pragma unroll
        for (int j = 0; j < NJ; j++) {
            int col = n0 + wn * WN + j * 16 + lr;
            float bs = bias[col];
            float vals[4];
#pragma unroll
            for (int r = 0; r < 4; r++) vals[r] = acc[i][j][r] + bs;
            if (EPI == EPI_F32RES) {
#pragma unroll
                for (int r = 0; r < 4; r++) {
                    int rr = rowb + r;
                    Cf[(size_t)rr * N + col] = vals[r] + res[(size_t)rr * N + col];
                }
            } else if (EPI == EPI_GELU) {
#pragma unroll
                for (int r = 0; r < 4; r++) {
                    float v = vals[r];
                    v = 0.5f * v * (1.f + erff(v * 0.70710678118654752f));
                    Cb[(size_t)(rowb + r) * N + col] = f2bf(v);
                }
            } else { // QKV scatter: Q/K [bh][seq][64] (Q pre-scaled), V [bh][64][seq]
                int comp = col >> 10, cw = col & 1023;
                int h = cw >> 6, d = cw & 63;
                int bb0 = rowb >> 11, ts = rowb & 2047;   // rowb%4==0: no batch crossing
                int bh = bb0 * NH + h;
                if (comp == 0) {
#pragma unroll
                    for (int r = 0; r < 4; r++)
                        qb[((size_t)bh * SEQ + ts + r) * HDIM + d] = f2bf(vals[r] * QSCALE);
                } else if (comp == 1) {
#pragma unroll
                    for (int r = 0; r < 4; r++)
                        kb[((size_t)bh * SEQ + ts + r) * HDIM + d] = f2bf(vals[r]);
                } else {
                    ushort4 pk;
                    pk.x = f2bf(vals[0]); pk.y = f2bf(vals[1]);
                    pk.z = f2bf(vals[2]); pk.w = f2bf(vals[3]);
                    *(ushort4*)&vb[((size_t)bh * HDIM + d) * SEQ + ts] = pk;
                }
            }
        }
    }
}

// ---------------- flash attention v2: S^T orientation, swizzled LDS, dbuf ------
// qb/kb: [bh][seq][64] bf16 (q pre-scaled by QSCALE); vb: [bh][64][seq] bf16
// Each block: q-tile pair (31-bx, bx) -> 33 k-tile iterations, perfectly balanced.
// LDS 40KB: QP (Q tile, reused as P buffer) + K dbuf + V dbuf, all XOR-swizzled:
//   chunk g (16B) of row r lives at byte r*128 + ((g ^ (r&7))*16).
__global__ __launch_bounds__(256, 4) void attn_mfma(const u16* __restrict__ qb,
                                                    const u16* __restrict__ kb,
                                                    const u16* __restrict__ vb,
                                                    u16* __restrict__ ctx)
{
    __shared__ __align__(16) char smem[40960];
    char* QP = smem;                        // 8KB Q tile / P buffer (wave-private rows)
    int bh = blockIdx.y, bb = bh >> 4, h = bh & 15;
    int t = threadIdx.x, lane = t & 63, w = t >> 6;
    int lr = lane & 15, lq = lane >> 4;
    int sw = (lr & 7) * 16;                 // read-side swizzle
    int cA = (lq * 16) ^ sw;                // chunk lq   (k-half 0)
    int cB = (64 | (lq * 16)) ^ sw;         // chunk 4+lq (k-half 1)
    // staging: thread covers LDS chunks t and t+256; swizzled global source
    int c0 = t,        r0 = c0 >> 3, g0 = (c0 & 7) ^ (r0 & 7);
    int c1 = t + 256,  r1 = c1 >> 3, g1 = (c1 & 7) ^ (r1 & 7);
    size_t off0  = (size_t)r0 * 128  + g0 * 16;   // Q/K tiles: 128B per row
    size_t off1  = (size_t)r1 * 128  + g1 * 16;
    size_t voff0 = (size_t)r0 * 4096 + g0 * 16;   // V: row=d, global stride 4096B
    size_t voff1 = (size_t)r1 * 4096 + g1 * 16;

    const char* qg_base = (const char*)qb + (size_t)bh * SEQ * 128;
    const char* kg_base = (const char*)kb + (size_t)bh * SEQ * 128;
    const char* vg_base = (const char*)vb + (size_t)bh * 64 * 4096;

    for (int pass = 0; pass < 2; ++pass) {
        int qt = pass ? blockIdx.x : (31 - blockIdx.x);
        if (pass) __syncthreads();          // QP/K0/V0 free before re-staging
        const char* qg = qg_base + (size_t)qt * 8192;
        async16(QP + c0 * 16, qg + off0);
        async16(QP + c1 * 16, qg + off1);
        async16(smem + 8192 + c0 * 16, kg_base + off0);
        async16(smem + 8192 + c1 * 16, kg_base + off1);
        async16(smem + 24576 + c0 * 16, vg_base + voff0);
        async16(smem + 24576 + c1 * 16, vg_base + voff1);

        float mold = -INFINITY, lsum = 0.f;
        f32x4 o[4];
#pragma unroll
        for (int dj = 0; dj < 4; dj++) o[dj] = (f32x4){0.f, 0.f, 0.f, 0.f};
        bf16x8 bq0, bq1;

        for (int kt = 0; kt <= qt; ++kt) {
            int cur = kt & 1;
            __syncthreads();                // tile kt ready; other buf free
            if (kt < qt) {                  // prefetch kt+1 (drained at next barrier)
                const char* kgn = kg_base + (size_t)(kt + 1) * 8192;
                const char* vgn = vg_base + (size_t)(kt + 1) * 128;
                char* Kn = smem + 8192  + (1 - cur) * 8192;
                char* Vn = smem + 24576 + (1 - cur) * 8192;
                async16(Kn + c0 * 16, kgn + off0);
                async16(Kn + c1 * 16, kgn + off1);
                async16(Vn + c0 * 16, vgn + voff0);
                async16(Vn + c1 * 16, vgn + voff1);
            }
            if (kt == 0) {                  // Q frags -> regs (QP then reused as P)
                const char* qr = QP + (w * 16 + lr) * 128;
                bq0 = *(const bf16x8*)(qr + cA);
                bq1 = *(const bf16x8*)(qr + cB);
            }
            const char* Kc = smem + 8192  + cur * 8192;
            const char* Vc = smem + 24576 + cur * 8192;

            // S^T = K Q^T : lane holds keys j*16+lq*4+r (rows), q = w*16+lr (col)
            float sv[4][4];
            bool diag = (kt == qt);
#pragma unroll
            for (int j = 0; j < 4; ++j) {
                const char* kr = Kc + (j * 16 + lr) * 128;
                bf16x8 ak0 = *(const bf16x8*)(kr + cA);
                bf16x8 ak1 = *(const bf16x8*)(kr + cB);
                f32x4 z = (f32x4){0.f, 0.f, 0.f, 0.f};
                z = __builtin_amdgcn_mfma_f32_16x16x32_bf16(ak0, bq0, z, 0, 0, 0);
                z = __builtin_amdgcn_mfma_f32_16x16x32_bf16(ak1, bq1, z, 0, 0, 0);
#pragma unroll
                for (int r = 0; r < 4; r++) {
                    float xv = z[r];
                    if (diag && (j * 16 + lq * 4 + r > w * 16 + lr)) xv = -INFINITY;
                    sv[j][r] = xv;
                }
            }
            // online softmax in exp2 domain; one q per lane
            float mx = sv[0][0];
#pragma unroll
            for (int j = 0; j < 4; j++)
#pragma unroll
                for (int r = 0; r < 4; r++) mx = fmaxf(mx, sv[j][r]);
            mx = fmaxf(mx, __shfl_xor(mx, 16));
            mx = fmaxf(mx, __shfl_xor(mx, 32));
            float mnew = fmaxf(mold, mx);
            float alpha = exp2f(mold - mnew);
            float rs = 0.f;
            unsigned pk[4][2];
#pragma unroll
            for (int j = 0; j < 4; j++)
#pragma unroll
                for (int hh = 0; hh < 2; hh++) {
                    float p0 = exp2f(sv[j][2 * hh]     - mnew);
                    float p1 = exp2f(sv[j][2 * hh + 1] - mnew);
                    rs += p0 + p1;
                    pk[j][hh] = (unsigned)f2bf(p0) | ((unsigned)f2bf(p1) << 16);
                }
            rs += __shfl_xor(rs, 16);
            rs += __shfl_xor(rs, 32);
            lsum = lsum * alpha + rs;
            mold = mnew;
#pragma unroll
            for (int dj = 0; dj < 4; dj++)
#pragma unroll
                for (int r = 0; r < 4; r++) o[dj][r] *= alpha;

            // P^T -> LDS (wave-private rows; no barrier): row q=w*16+lr, b64 writes
            {
                char* pw = QP + (w * 16 + lr) * 128 + (lq & 1) * 8;
#pragma unroll
                for (int j = 0; j < 4; j++) {
                    int pos = ((j * 2 + (lq >> 1)) * 16) ^ sw;
                    uint2 u; u.x = pk[j][0]; u.y = pk[j][1];
                    *(uint2*)(pw + pos) = u;
                }
            }
            asm volatile("s_waitcnt lgkmcnt(0)" ::: "memory");
            const char* pr = QP + (w * 16 + lr) * 128;
            bf16x8 bp0 = *(const bf16x8*)(pr + cA);
            bf16x8 bp1 = *(const bf16x8*)(pr + cB);
            // O^T += V^T P^T : rows d, cols q
#pragma unroll
            for (int dj = 0; dj < 4; ++dj) {
                const char* vr = Vc + (dj * 16 + lr) * 128;
                bf16x8 av0 = *(const bf16x8*)(vr + cA);
                bf16x8 av1 = *(const bf16x8*)(vr + cB);
                o[dj] = __builtin_amdgcn_mfma_f32_16x16x32_bf16(av0, bp0, o[dj], 0, 0, 0);
                o[dj] = __builtin_amdgcn_mfma_f32_16x16x32_bf16(av1, bp1, o[dj], 0, 0, 0);
            }
        }

        float inv = 1.f / lsum;
        int tok = qt * 64 + w * 16 + lr;
        u16* cp = ctx + ((size_t)(bb * SEQ) + tok) * TD + h * HDIM + lq * 4;
#pragma unroll
        for (int dj = 0; dj < 4; dj++) {
            ushort4 s4;
            s4.x = f2bf(o[dj][0] * inv); s4.y = f2bf(o[dj][1] * inv);
            s4.z = f2bf(o[dj][2] * inv); s4.w = f2bf(o[dj][3] * inv);
            *(ushort4*)(cp + dj * 16) = s4;
        }
    }
}

extern "C" void kernel_launch(void* const* d_in, const int* in_sizes, int n_in,
                              void* d_out, int out_size, void* d_ws, size_t ws_size,
                              hipStream_t stream)
{
    const float* x    = (const float*)d_in[0];
    const float* g1   = (const float*)d_in[1];
    const float* b1   = (const float*)d_in[2];
    const float* Wqkv = (const float*)d_in[3];
    const float* bqkv = (const float*)d_in[4];
    const float* Wo   = (const float*)d_in[5];
    const float* bo   = (const float*)d_in[6];
    const float* g2   = (const float*)d_in[7];
    const float* b2   = (const float*)d_in[8];
    const float* W1   = (const float*)d_in[9];
    const float* b1f  = (const float*)d_in[10];
    const float* W2   = (const float*)d_in[11];
    const float* b2f  = (const float*)d_in[12];
    float* out = (float*)d_out;

    char* ws = (char*)d_ws;
    const size_t MB = 1ull << 20;
    u16* wqkvT = (u16*)(ws + 0 * MB);    // 6 MB  [3072][1024]
    u16* woT   = (u16*)(ws + 6 * MB);    // 2 MB  [1024][1024]
    u16* w1T   = (u16*)(ws + 8 * MB);    // 8 MB  [4096][1024]
    u16* w2T   = (u16*)(ws + 16 * MB);   // 8 MB  [1024][4096]
    u16* qbuf  = (u16*)(ws + 24 * MB);   // 8 MB  [32][2048][64] (pre-scaled)
    u16* kbuf  = (u16*)(ws + 32 * MB);   // 8 MB
    u16* vbuf  = (u16*)(ws + 40 * MB);   // 8 MB  [32][64][2048]
    u16* hbuf  = (u16*)(ws + 48 * MB);   // 8 MB  h then hh
    u16* ctx   = (u16*)(ws + 56 * MB);   // 8 MB
    float* x2  = (float*)(ws + 64 * MB); // 16 MB
    u16* ff1   = (u16*)(ws + 80 * MB);   // 32 MB  -> 112 MB total

    wconv_all<<<3072, 256, 0, stream>>>(Wqkv, Wo, W1, W2, wqkvT, woT, w1T, w2T);

    ln_bf16<<<NROWS, 256, 0, stream>>>(x, g1, b1, hbuf);
    gemm_mfma<EPI_QKV, 128, 32><<<dim3(3 * TD / 128, NROWS / 128), 256, 0, stream>>>(
        NROWS, 3 * TD, TD, hbuf, wqkvT, bqkv, nullptr, nullptr, nullptr, qbuf, kbuf, vbuf);
    attn_mfma<<<dim3(16, NB * NH), 256, 0, stream>>>(qbuf, kbuf, vbuf, ctx);
    gemm_mfma<EPI_F32RES, 64, 64><<<dim3(TD / 64, NROWS / 128), 256, 0, stream>>>(
        NROWS, TD, TD, ctx, woT, bo, x, x2, nullptr, nullptr, nullptr, nullptr);
    ln_bf16<<<NROWS, 256, 0, stream>>>(x2, g2, b2, hbuf);
    gemm_mfma<EPI_GELU, 128, 32><<<dim3(FFD / 128, NROWS / 128), 256, 0, stream>>>(
        NROWS, FFD, TD, hbuf, w1T, b1f, nullptr, nullptr, ff1, nullptr, nullptr, nullptr);
    gemm_mfma<EPI_F32RES, 64, 64><<<dim3(TD / 64, NROWS / 128), 256, 0, stream>>>(
        NROWS, TD, FFD, ff1, w2T, b2f, x2, out, nullptr, nullptr, nullptr, nullptr);
}

// Round 7
// 334.446 us; speedup vs baseline: 6.4599x; 1.0022x over previous
//
#include <hip/hip_runtime.h>
#include <math.h>

#define TD 1024      // model dim
#define NH 16        // heads
#define HDIM 64      // head dim
#define SEQ 2048     // seq len
#define NB 2         // batch
#define NROWS 4096   // NB*SEQ
#define FFD 4096     // ffn dim

// 1/sqrt(64) * log2(e): softmax computed in exp2 domain; folded into Q at QKV epilogue
#define QSCALE 0.18033688011112042f

typedef unsigned short u16;
typedef __attribute__((ext_vector_type(8))) short bf16x8;   // 8 bf16 = 4 VGPR
typedef __attribute__((ext_vector_type(4))) float f32x4;    // MFMA acc

__device__ __forceinline__ u16 f2bf(float f) {
    union { float f; unsigned u; } v; v.f = f;
    return (u16)((v.u + 0x7FFFu + ((v.u >> 16) & 1u)) >> 16);
}

// async global->LDS, 16B per lane. LDS dest must be wave-uniform base + lane*16.
__device__ __forceinline__ void async16(void* lds, const void* g) {
    __builtin_amdgcn_global_load_lds(
        (const __attribute__((address_space(1))) unsigned*)g,
        (__attribute__((address_space(3))) unsigned*)lds, 16, 0, 0);
}

// ---------------- LayerNorm -> bf16 out: one block per row of 1024 -------------
__global__ __launch_bounds__(256) void ln_bf16(const float* __restrict__ x,
                                               const float* __restrict__ g,
                                               const float* __restrict__ b,
                                               u16* __restrict__ out)
{
    int row = blockIdx.x;
    const float* xr = x + (size_t)row * TD;
    u16* outr = out + (size_t)row * TD;
    int t = threadIdx.x;
    float v[4];
    float s = 0.f, ss = 0.f;
#pragma unroll
    for (int i = 0; i < 4; i++) {
        v[i] = xr[t + 256 * i];
        s += v[i];
        ss += v[i] * v[i];
    }
#pragma unroll
    for (int o = 32; o > 0; o >>= 1) {
        s  += __shfl_down(s, o);
        ss += __shfl_down(ss, o);
    }
    __shared__ float sm[4], sm2[4];
    int wave = t >> 6, lane = t & 63;
    if (lane == 0) { sm[wave] = s; sm2[wave] = ss; }
    __syncthreads();
    s  = sm[0] + sm[1] + sm[2] + sm[3];
    ss = sm2[0] + sm2[1] + sm2[2] + sm2[3];
    float mu  = s * (1.f / TD);
    float var = ss * (1.f / TD) - mu * mu;
    float rstd = rsqrtf(var + 1e-5f);
#pragma unroll
    for (int i = 0; i < 4; i++) {
        int c = t + 256 * i;
        outr[c] = f2bf((v[i] - mu) * rstd * g[c] + b[c]);
    }
}

// ------- fused weight convert+transpose: all four W[K][N] fp32 -> Wt[N][K] bf16 -
__global__ __launch_bounds__(256) void wconv_all(
    const float* __restrict__ Wqkv, const float* __restrict__ Wo,
    const float* __restrict__ W1,   const float* __restrict__ W2,
    u16* __restrict__ wqkvT, u16* __restrict__ woT,
    u16* __restrict__ w1T,   u16* __restrict__ w2T)
{
    int blk = blockIdx.x;
    const float* W; u16* Wt; int K, N, local, nx;
    if (blk < 768)       { W = Wqkv; Wt = wqkvT; K = TD;  N = 3 * TD; local = blk;        nx = 48; }
    else if (blk < 1024) { W = Wo;   Wt = woT;   K = TD;  N = TD;     local = blk - 768;  nx = 16; }
    else if (blk < 2048) { W = W1;   Wt = w1T;   K = TD;  N = FFD;    local = blk - 1024; nx = 64; }
    else                 { W = W2;   Wt = w2T;   K = FFD; N = TD;     local = blk - 2048; nx = 16; }
    int n0 = (local % nx) * 64, k0 = (local / nx) * 64;
    __shared__ u16 tile[64][65];
    int t = threadIdx.x, c = t & 63, rq = t >> 6;
#pragma unroll
    for (int i = 0; i < 16; i++) {
        int r = rq * 16 + i;
        tile[r][c] = f2bf(W[(size_t)(k0 + r) * N + n0 + c]);
    }
    __syncthreads();
#pragma unroll
    for (int i = 0; i < 16; i++) {
        int r = rq * 16 + i;
        Wt[(size_t)(n0 + r) * K + k0 + c] = tile[c][r];
    }
}

// ---------------- bf16 MFMA GEMM: 128xTN tile, BK k-slab, dbuf LDS -------------
// C[M,N] = A[M,K] @ Bt[N,K]^T + bias, with epilogues.
// Pipeline: one barrier per K-step; prefetch of slab k+1 issued right AFTER the
// barrier that publishes slab k -> vmcnt(0) drain at the next barrier waits on
// loads that had a full compute phase (~2x latency at BK=64) in flight.
// LDS swizzle: within each 64B k-half of a row, 16B chunk g stored at slot
// g ^ ((row>>1)&3). Frag reads hit all 8 bank groups, 2-way only (free).
// XCD swizzle: tiles remapped so all N-tiles of an M-row land on one XCD's L2.
#define EPI_QKV 0
#define EPI_F32RES 1
#define EPI_GELU 2

template<int EPI, int TN, int BK>
__global__ __launch_bounds__(256) void gemm_mfma(int M, int N, int K,
    const u16* __restrict__ A, const u16* __restrict__ Bt,
    const float* __restrict__ bias, const float* __restrict__ res,
    float* __restrict__ Cf, u16* __restrict__ Cb,
    u16* __restrict__ qb, u16* __restrict__ kb, u16* __restrict__ vb)
{
    constexpr int WN  = TN / 2;               // per-wave N extent (2 waves along N)
    constexpr int NJ  = WN / 16;              // B frags per wave
    constexpr int KH  = BK / 32;              // 32-elem k-halves per slab
    constexpr int CPR = BK / 8;               // 16B chunks per tile-row
    constexpr int ACH = (128 * CPR) / 256;    // A chunks per thread
    constexpr int BCH = (TN  * CPR) / 256;    // B chunks per thread
    constexpr int ASZ = 128 * BK * 2;         // bytes per A buffer
    constexpr int BSZ = TN  * BK * 2;
    __shared__ __align__(16) char smem[2 * (ASZ + BSZ)];

    int t = threadIdx.x;
    int lane = t & 63, w = t >> 6;
    int wm = w >> 1, wn = w & 1;              // 2x2 wave grid: wave = 64(M) x WN(N)
    int lr = lane & 15, lq = lane >> 4;
    // XCD-aware tile remap (gridDim.y % 8 == 0 for all our launches)
    int gx = gridDim.x;
    int lin = blockIdx.x + gx * blockIdx.y;
    int li = lin >> 3;
    int qy = li / gx;
    int ty = (lin & 7) * (gridDim.y >> 3) + qy;
    int tx = li - qy * gx;
    int m0 = ty * 128, n0 = tx * TN;
    int swc = (lq ^ ((lr >> 1) & 3)) * 16;    // swizzled frag-read chunk offset

    // per-thread staging source pointers (bumped by BK each slab)
    const u16* ap[ACH];
    const u16* bp[BCH];
#pragma unroll
    for (int i = 0; i < ACH; i++) {
        int c = t + 256 * i, r = c / CPR, ww = c % CPR;
        int g = (ww & ~3) | ((ww & 3) ^ ((r >> 1) & 3));
        ap[i] = A + (size_t)(m0 + r) * K + g * 8;
    }
#pragma unroll
    for (int i = 0; i < BCH; i++) {
        int c = t + 256 * i, r = c / CPR, ww = c % CPR;
        int g = (ww & ~3) | ((ww & 3) ^ ((r >> 1) & 3));
        bp[i] = Bt + (size_t)(n0 + r) * K + g * 8;
    }

    f32x4 acc[4][NJ];
#pragma unroll
    for (int i = 0; i < 4; i++)
#pragma unroll
        for (int j = 0; j < NJ; j++) acc[i][j] = (f32x4){0.f, 0.f, 0.f, 0.f};

    // prologue: stage slab 0 into buffer 0
#pragma unroll
    for (int i = 0; i < ACH; i++)
        async16(smem + (t + 256 * i) * 16, ap[i]);
#pragma unroll
    for (int i = 0; i < BCH; i++)
        async16(smem + 2 * ASZ + (t + 256 * i) * 16, bp[i]);

    int nk = K / BK;
    for (int kt = 0; kt < nk; kt++) {
        int cur = kt & 1;
        __syncthreads();                      // slab kt ready; other buffer free
        if (kt + 1 < nk) {                    // prefetch slab kt+1 (drains at next barrier)
            char* An = smem + (1 - cur) * ASZ;
            char* Bn = smem + 2 * ASZ + (1 - cur) * BSZ;
#pragma unroll
            for (int i = 0; i < ACH; i++) {
                ap[i] += BK;
                async16(An + (t + 256 * i) * 16, ap[i]);
            }
#pragma unroll
            for (int i = 0; i < BCH; i++) {
                bp[i] += BK;
                async16(Bn + (t + 256 * i) * 16, bp[i]);
            }
        }
        const char* Ac = smem + cur * ASZ;
        const char* Bc = smem + 2 * ASZ + cur * BSZ;
#pragma unroll
        for (int h = 0; h < KH; h++) {
            bf16x8 af[4], bfr[NJ];
#pragma unroll
            for (int i = 0; i < 4; i++)
                af[i] = *(const bf16x8*)(Ac + (wm * 64 + i * 16 + lr) * (2 * BK) + h * 64 + swc);
#pragma unroll
            for (int j = 0; j < NJ; j++)
                bfr[j] = *(const bf16x8*)(Bc + (wn * WN + j * 16 + lr) * (2 * BK) + h * 64 + swc);
#pragma unroll
            for (int i = 0; i < 4; i++)
#pragma unroll
                for (int j = 0; j < NJ; j++)
                    acc[i][j] = __builtin_amdgcn_mfma_f32_16x16x32_bf16(af[i], bfr[j], acc[i][j], 0, 0, 0);
        }
    }

#pragma unroll
    for (int i = 0; i < 4; i++) {
        int rowb = m0 + wm * 64 + i * 16 + lq * 4;
#pragma unroll
        for (int j = 0; j < NJ; j++) {
            int col = n0 + wn * WN + j * 16 + lr;
            float bs = bias[col];
            float vals[4];
#pragma unroll
            for (int r = 0; r < 4; r++) vals[r] = acc[i][j][r] + bs;
            if (EPI == EPI_F32RES) {
#pragma unroll
                for (int r = 0; r < 4; r++) {
                    int rr = rowb + r;
                    Cf[(size_t)rr * N + col] = vals[r] + res[(size_t)rr * N + col];
                }
            } else if (EPI == EPI_GELU) {
#pragma unroll
                for (int r = 0; r < 4; r++) {
                    float v = vals[r];
                    v = 0.5f * v * (1.f + erff(v * 0.70710678118654752f));
                    Cb[(size_t)(rowb + r) * N + col] = f2bf(v);
                }
            } else { // QKV scatter: Q/K [bh][seq][64] (Q pre-scaled), V [bh][64][seq]
                int comp = col >> 10, cw = col & 1023;
                int h = cw >> 6, d = cw & 63;
                int bb0 = rowb >> 11, ts = rowb & 2047;   // rowb%4==0: no batch crossing
                int bh = bb0 * NH + h;
                if (comp == 0) {
#pragma unroll
                    for (int r = 0; r < 4; r++)
                        qb[((size_t)bh * SEQ + ts + r) * HDIM + d] = f2bf(vals[r] * QSCALE);
                } else if (comp == 1) {
#pragma unroll
                    for (int r = 0; r < 4; r++)
                        kb[((size_t)bh * SEQ + ts + r) * HDIM + d] = f2bf(vals[r]);
                } else {
                    ushort4 pk;
                    pk.x = f2bf(vals[0]); pk.y = f2bf(vals[1]);
                    pk.z = f2bf(vals[2]); pk.w = f2bf(vals[3]);
                    *(ushort4*)&vb[((size_t)bh * HDIM + d) * SEQ + ts] = pk;
                }
            }
        }
    }
}

// ---------------- flash attention v2: S^T orientation, swizzled LDS, dbuf ------
// qb/kb: [bh][seq][64] bf16 (q pre-scaled by QSCALE); vb: [bh][64][seq] bf16
// Each block: q-tile pair (31-bx, bx) -> 33 k-tile iterations, perfectly balanced.
// LDS 40KB: QP (Q tile, reused as P buffer) + K dbuf + V dbuf, all XOR-swizzled:
//   chunk g (16B) of row r lives at byte r*128 + ((g ^ (r&7))*16).
__global__ __launch_bounds__(256, 4) void attn_mfma(const u16* __restrict__ qb,
                                                    const u16* __restrict__ kb,
                                                    const u16* __restrict__ vb,
                                                    u16* __restrict__ ctx)
{
    __shared__ __align__(16) char smem[40960];
    char* QP = smem;                        // 8KB Q tile / P buffer (wave-private rows)
    int bh = blockIdx.y, bb = bh >> 4, h = bh & 15;
    int t = threadIdx.x, lane = t & 63, w = t >> 6;
    int lr = lane & 15, lq = lane >> 4;
    int sw = (lr & 7) * 16;                 // read-side swizzle
    int cA = (lq * 16) ^ sw;                // chunk lq   (k-half 0)
    int cB = (64 | (lq * 16)) ^ sw;         // chunk 4+lq (k-half 1)
    // staging: thread covers LDS chunks t and t+256; swizzled global source
    int c0 = t,        r0 = c0 >> 3, g0 = (c0 & 7) ^ (r0 & 7);
    int c1 = t + 256,  r1 = c1 >> 3, g1 = (c1 & 7) ^ (r1 & 7);
    size_t off0  = (size_t)r0 * 128  + g0 * 16;   // Q/K tiles: 128B per row
    size_t off1  = (size_t)r1 * 128  + g1 * 16;
    size_t voff0 = (size_t)r0 * 4096 + g0 * 16;   // V: row=d, global stride 4096B
    size_t voff1 = (size_t)r1 * 4096 + g1 * 16;

    const char* qg_base = (const char*)qb + (size_t)bh * SEQ * 128;
    const char* kg_base = (const char*)kb + (size_t)bh * SEQ * 128;
    const char* vg_base = (const char*)vb + (size_t)bh * 64 * 4096;

    for (int pass = 0; pass < 2; ++pass) {
        int qt = pass ? blockIdx.x : (31 - blockIdx.x);
        if (pass) __syncthreads();          // QP/K0/V0 free before re-staging
        const char* qg = qg_base + (size_t)qt * 8192;
        async16(QP + c0 * 16, qg + off0);
        async16(QP + c1 * 16, qg + off1);
        async16(smem + 8192 + c0 * 16, kg_base + off0);
        async16(smem + 8192 + c1 * 16, kg_base + off1);
        async16(smem + 24576 + c0 * 16, vg_base + voff0);
        async16(smem + 24576 + c1 * 16, vg_base + voff1);

        float mold = -INFINITY, lsum = 0.f;
        f32x4 o[4];
#pragma unroll
        for (int dj = 0; dj < 4; dj++) o[dj] = (f32x4){0.f, 0.f, 0.f, 0.f};
        bf16x8 bq0, bq1;

        for (int kt = 0; kt <= qt; ++kt) {
            int cur = kt & 1;
            __syncthreads();                // tile kt ready; other buf free
            if (kt < qt) {                  // prefetch kt+1 (drained at next barrier)
                const char* kgn = kg_base + (size_t)(kt + 1) * 8192;
                const char* vgn = vg_base + (size_t)(kt + 1) * 128;
                char* Kn = smem + 8192  + (1 - cur) * 8192;
                char* Vn = smem + 24576 + (1 - cur) * 8192;
                async16(Kn + c0 * 16, kgn + off0);
                async16(Kn + c1 * 16, kgn + off1);
                async16(Vn + c0 * 16, vgn + voff0);
                async16(Vn + c1 * 16, vgn + voff1);
            }
            if (kt == 0) {                  // Q frags -> regs (QP then reused as P)
                const char* qr = QP + (w * 16 + lr) * 128;
                bq0 = *(const bf16x8*)(qr + cA);
                bq1 = *(const bf16x8*)(qr + cB);
            }
            const char* Kc = smem + 8192  + cur * 8192;
            const char* Vc = smem + 24576 + cur * 8192;

            // S^T = K Q^T : lane holds keys j*16+lq*4+r (rows), q = w*16+lr (col)
            float sv[4][4];
            bool diag = (kt == qt);
#pragma unroll
            for (int j = 0; j < 4; ++j) {
                const char* kr = Kc + (j * 16 + lr) * 128;
                bf16x8 ak0 = *(const bf16x8*)(kr + cA);
                bf16x8 ak1 = *(const bf16x8*)(kr + cB);
                f32x4 z = (f32x4){0.f, 0.f, 0.f, 0.f};
                z = __builtin_amdgcn_mfma_f32_16x16x32_bf16(ak0, bq0, z, 0, 0, 0);
                z = __builtin_amdgcn_mfma_f32_16x16x32_bf16(ak1, bq1, z, 0, 0, 0);
#pragma unroll
                for (int r = 0; r < 4; r++) {
                    float xv = z[r];
                    if (diag && (j * 16 + lq * 4 + r > w * 16 + lr)) xv = -INFINITY;
                    sv[j][r] = xv;
                }
            }
            // online softmax in exp2 domain; one q per lane
            float mx = sv[0][0];
#pragma unroll
            for (int j = 0; j < 4; j++)
#pragma unroll
                for (int r = 0; r < 4; r++) mx = fmaxf(mx, sv[j][r]);
            mx = fmaxf(mx, __shfl_xor(mx, 16));
            mx = fmaxf(mx, __shfl_xor(mx, 32));
            float mnew = fmaxf(mold, mx);
            float alpha = exp2f(mold - mnew);
            float rs = 0.f;
            unsigned pk[4][2];
#pragma unroll
            for (int j = 0; j < 4; j++)
#pragma unroll
                for (int hh = 0; hh < 2; hh++) {
                    float p0 = exp2f(sv[j][2 * hh]     - mnew);
                    float p1 = exp2f(sv[j][2 * hh + 1] - mnew);
                    rs += p0 + p1;
                    pk[j][hh] = (unsigned)f2bf(p0) | ((unsigned)f2bf(p1) << 16);
                }
            rs += __shfl_xor(rs, 16);
            rs += __shfl_xor(rs, 32);
            lsum = lsum * alpha + rs;
            mold = mnew;
#pragma unroll
            for (int dj = 0; dj < 4; dj++)
#pragma unroll
                for (int r = 0; r < 4; r++) o[dj][r] *= alpha;

            // P^T -> LDS (wave-private rows; no barrier): row q=w*16+lr, b64 writes
            {
                char* pw = QP + (w * 16 + lr) * 128 + (lq & 1) * 8;
#pragma unroll
                for (int j = 0; j < 4; j++) {
                    int pos = ((j * 2 + (lq >> 1)) * 16) ^ sw;
                    uint2 u; u.x = pk[j][0]; u.y = pk[j][1];
                    *(uint2*)(pw + pos) = u;
                }
            }
            asm volatile("s_waitcnt lgkmcnt(0)" ::: "memory");
            const char* pr = QP + (w * 16 + lr) * 128;
            bf16x8 bp0 = *(const bf16x8*)(pr + cA);
            bf16x8 bp1 = *(const bf16x8*)(pr + cB);
            // O^T += V^T P^T : rows d, cols q
#pragma unroll
            for (int dj = 0; dj < 4; ++dj) {
                const char* vr = Vc + (dj * 16 + lr) * 128;
                bf16x8 av0 = *(const bf16x8*)(vr + cA);
                bf16x8 av1 = *(const bf16x8*)(vr + cB);
                o[dj] = __builtin_amdgcn_mfma_f32_16x16x32_bf16(av0, bp0, o[dj], 0, 0, 0);
                o[dj] = __builtin_amdgcn_mfma_f32_16x16x32_bf16(av1, bp1, o[dj], 0, 0, 0);
            }
        }

        float inv = 1.f / lsum;
        int tok = qt * 64 + w * 16 + lr;
        u16* cp = ctx + ((size_t)(bb * SEQ) + tok) * TD + h * HDIM + lq * 4;
#pragma unroll
        for (int dj = 0; dj < 4; dj++) {
            ushort4 s4;
            s4.x = f2bf(o[dj][0] * inv); s4.y = f2bf(o[dj][1] * inv);
            s4.z = f2bf(o[dj][2] * inv); s4.w = f2bf(o[dj][3] * inv);
            *(ushort4*)(cp + dj * 16) = s4;
        }
    }
}

extern "C" void kernel_launch(void* const* d_in, const int* in_sizes, int n_in,
                              void* d_out, int out_size, void* d_ws, size_t ws_size,
                              hipStream_t stream)
{
    const float* x    = (const float*)d_in[0];
    const float* g1   = (const float*)d_in[1];
    const float* b1   = (const float*)d_in[2];
    const float* Wqkv = (const float*)d_in[3];
    const float* bqkv = (const float*)d_in[4];
    const float* Wo   = (const float*)d_in[5];
    const float* bo   = (const float*)d_in[6];
    const float* g2   = (const float*)d_in[7];
    const float* b2   = (const float*)d_in[8];
    const float* W1   = (const float*)d_in[9];
    const float* b1f  = (const float*)d_in[10];
    const float* W2   = (const float*)d_in[11];
    const float* b2f  = (const float*)d_in[12];
    float* out = (float*)d_out;

    char* ws = (char*)d_ws;
    const size_t MB = 1ull << 20;
    u16* wqkvT = (u16*)(ws + 0 * MB);    // 6 MB  [3072][1024]
    u16* woT   = (u16*)(ws + 6 * MB);    // 2 MB  [1024][1024]
    u16* w1T   = (u16*)(ws + 8 * MB);    // 8 MB  [4096][1024]
    u16* w2T   = (u16*)(ws + 16 * MB);   // 8 MB  [1024][4096]
    u16* qbuf  = (u16*)(ws + 24 * MB);   // 8 MB  [32][2048][64] (pre-scaled)
    u16* kbuf  = (u16*)(ws + 32 * MB);   // 8 MB
    u16* vbuf  = (u16*)(ws + 40 * MB);   // 8 MB  [32][64][2048]
    u16* hbuf  = (u16*)(ws + 48 * MB);   // 8 MB  h then hh
    u16* ctx   = (u16*)(ws + 56 * MB);   // 8 MB
    float* x2  = (float*)(ws + 64 * MB); // 16 MB
    u16* ff1   = (u16*)(ws + 80 * MB);   // 32 MB  -> 112 MB total

    wconv_all<<<3072, 256, 0, stream>>>(Wqkv, Wo, W1, W2, wqkvT, woT, w1T, w2T);

    ln_bf16<<<NROWS, 256, 0, stream>>>(x, g1, b1, hbuf);
    gemm_mfma<EPI_QKV, 128, 64><<<dim3(3 * TD / 128, NROWS / 128), 256, 0, stream>>>(
        NROWS, 3 * TD, TD, hbuf, wqkvT, bqkv, nullptr, nullptr, nullptr, qbuf, kbuf, vbuf);
    attn_mfma<<<dim3(16, NB * NH), 256, 0, stream>>>(qbuf, kbuf, vbuf, ctx);
    gemm_mfma<EPI_F32RES, 64, 64><<<dim3(TD / 64, NROWS / 128), 256, 0, stream>>>(
        NROWS, TD, TD, ctx, woT, bo, x, x2, nullptr, nullptr, nullptr, nullptr);
    ln_bf16<<<NROWS, 256, 0, stream>>>(x2, g2, b2, hbuf);
    gemm_mfma<EPI_GELU, 128, 64><<<dim3(FFD / 128, NROWS / 128), 256, 0, stream>>>(
        NROWS, FFD, TD, hbuf, w1T, b1f, nullptr, nullptr, ff1, nullptr, nullptr, nullptr);
    gemm_mfma<EPI_F32RES, 64, 64><<<dim3(TD / 64, NROWS / 128), 256, 0, stream>>>(
        NROWS, TD, FFD, ff1, w2T, b2f, x2, out, nullptr, nullptr, nullptr, nullptr);
}

// Round 8
// 328.049 us; speedup vs baseline: 6.5859x; 1.0195x over previous
//
#include <hip/hip_runtime.h>
#include <math.h>

#define TD 1024      // model dim
#define NH 16        // heads
#define HDIM 64      // head dim
#define SEQ 2048     // seq len
#define NB 2         // batch
#define NROWS 4096   // NB*SEQ
#define FFD 4096     // ffn dim

// 1/sqrt(64) * log2(e): softmax computed in exp2 domain; folded into Q at QKV epilogue
#define QSCALE 0.18033688011112042f

typedef unsigned short u16;
typedef __attribute__((ext_vector_type(8))) short bf16x8;   // 8 bf16 = 4 VGPR
typedef __attribute__((ext_vector_type(4))) float f32x4;    // MFMA acc

__device__ __forceinline__ u16 f2bf(float f) {
    union { float f; unsigned u; } v; v.f = f;
    return (u16)((v.u + 0x7FFFu + ((v.u >> 16) & 1u)) >> 16);
}

// async global->LDS, 16B per lane. LDS dest must be wave-uniform base + lane*16.
__device__ __forceinline__ void async16(void* lds, const void* g) {
    __builtin_amdgcn_global_load_lds(
        (const __attribute__((address_space(1))) unsigned*)g,
        (__attribute__((address_space(3))) unsigned*)lds, 16, 0, 0);
}

// ---------------- LayerNorm -> bf16 out: one block per row of 1024 -------------
__global__ __launch_bounds__(256) void ln_bf16(const float* __restrict__ x,
                                               const float* __restrict__ g,
                                               const float* __restrict__ b,
                                               u16* __restrict__ out)
{
    int row = blockIdx.x;
    const float* xr = x + (size_t)row * TD;
    u16* outr = out + (size_t)row * TD;
    int t = threadIdx.x;
    float v[4];
    float s = 0.f, ss = 0.f;
#pragma unroll
    for (int i = 0; i < 4; i++) {
        v[i] = xr[t + 256 * i];
        s += v[i];
        ss += v[i] * v[i];
    }
#pragma unroll
    for (int o = 32; o > 0; o >>= 1) {
        s  += __shfl_down(s, o);
        ss += __shfl_down(ss, o);
    }
    __shared__ float sm[4], sm2[4];
    int wave = t >> 6, lane = t & 63;
    if (lane == 0) { sm[wave] = s; sm2[wave] = ss; }
    __syncthreads();
    s  = sm[0] + sm[1] + sm[2] + sm[3];
    ss = sm2[0] + sm2[1] + sm2[2] + sm2[3];
    float mu  = s * (1.f / TD);
    float var = ss * (1.f / TD) - mu * mu;
    float rstd = rsqrtf(var + 1e-5f);
#pragma unroll
    for (int i = 0; i < 4; i++) {
        int c = t + 256 * i;
        outr[c] = f2bf((v[i] - mu) * rstd * g[c] + b[c]);
    }
}

// --- prep: fused weight convert+transpose (blocks 0..3071) + LN1 (3072..7167) --
__global__ __launch_bounds__(256) void prep_kernel(
    const float* __restrict__ Wqkv, const float* __restrict__ Wo,
    const float* __restrict__ W1,   const float* __restrict__ W2,
    u16* __restrict__ wqkvT, u16* __restrict__ woT,
    u16* __restrict__ w1T,   u16* __restrict__ w2T,
    const float* __restrict__ x, const float* __restrict__ g1,
    const float* __restrict__ b1, u16* __restrict__ hbuf)
{
    int blk = blockIdx.x;
    int t = threadIdx.x;
    if (blk >= 3072) {               // ---- LN1 path ----
        int row = blk - 3072;
        const float* xr = x + (size_t)row * TD;
        u16* outr = hbuf + (size_t)row * TD;
        float v[4];
        float s = 0.f, ss = 0.f;
#pragma unroll
        for (int i = 0; i < 4; i++) {
            v[i] = xr[t + 256 * i];
            s += v[i];
            ss += v[i] * v[i];
        }
#pragma unroll
        for (int o = 32; o > 0; o >>= 1) {
            s  += __shfl_down(s, o);
            ss += __shfl_down(ss, o);
        }
        __shared__ float sm[4], sm2[4];
        int wave = t >> 6, lane = t & 63;
        if (lane == 0) { sm[wave] = s; sm2[wave] = ss; }
        __syncthreads();
        s  = sm[0] + sm[1] + sm[2] + sm[3];
        ss = sm2[0] + sm2[1] + sm2[2] + sm2[3];
        float mu  = s * (1.f / TD);
        float var = ss * (1.f / TD) - mu * mu;
        float rstd = rsqrtf(var + 1e-5f);
#pragma unroll
        for (int i = 0; i < 4; i++) {
            int c = t + 256 * i;
            outr[c] = f2bf((v[i] - mu) * rstd * g1[c] + b1[c]);
        }
        return;
    }
    // ---- weight transpose path ----
    const float* W; u16* Wt; int K, N, local, nx;
    if (blk < 768)       { W = Wqkv; Wt = wqkvT; K = TD;  N = 3 * TD; local = blk;        nx = 48; }
    else if (blk < 1024) { W = Wo;   Wt = woT;   K = TD;  N = TD;     local = blk - 768;  nx = 16; }
    else if (blk < 2048) { W = W1;   Wt = w1T;   K = TD;  N = FFD;    local = blk - 1024; nx = 64; }
    else                 { W = W2;   Wt = w2T;   K = FFD; N = TD;     local = blk - 2048; nx = 16; }
    int n0 = (local % nx) * 64, k0 = (local / nx) * 64;
    __shared__ u16 tile[64][65];
    int c = t & 63, rq = t >> 6;
#pragma unroll
    for (int i = 0; i < 16; i++) {
        int r = rq * 16 + i;
        tile[r][c] = f2bf(W[(size_t)(k0 + r) * N + n0 + c]);
    }
    __syncthreads();
#pragma unroll
    for (int i = 0; i < 16; i++) {
        int r = rq * 16 + i;
        Wt[(size_t)(n0 + r) * K + k0 + c] = tile[c][r];
    }
}

// ---------------- bf16 MFMA GEMM: 128xTN tile, BK k-slab, dbuf LDS -------------
// C[M,N] = A[M,K] @ Bt[N,K]^T + bias, with epilogues.
// Pipeline: one barrier per K-step; prefetch of slab k+1 issued right AFTER the
// barrier that publishes slab k -> vmcnt(0) drain at the next barrier waits on
// loads that had a full compute phase in flight.
// LDS swizzle: within each 64B k-half of a row, 16B chunk g stored at slot
// g ^ ((row>>1)&3). Frag reads hit all 8 bank groups, 2-way only (free).
// XCD swizzle: tiles remapped so all N-tiles of an M-row land on one XCD's L2.
#define EPI_QKV 0
#define EPI_F32RES 1
#define EPI_GELU 2

template<int EPI, int TN, int BK>
__global__ __launch_bounds__(256) void gemm_mfma(int M, int N, int K,
    const u16* __restrict__ A, const u16* __restrict__ Bt,
    const float* __restrict__ bias, const float* __restrict__ res,
    float* __restrict__ Cf, u16* __restrict__ Cb,
    u16* __restrict__ qb, u16* __restrict__ kb, u16* __restrict__ vb)
{
    constexpr int WN  = TN / 2;               // per-wave N extent (2 waves along N)
    constexpr int NJ  = WN / 16;              // B frags per wave
    constexpr int KH  = BK / 32;              // 32-elem k-halves per slab
    constexpr int CPR = BK / 8;               // 16B chunks per tile-row
    constexpr int ACH = (128 * CPR) / 256;    // A chunks per thread
    constexpr int BCH = (TN  * CPR) / 256;    // B chunks per thread
    constexpr int ASZ = 128 * BK * 2;         // bytes per A buffer
    constexpr int BSZ = TN  * BK * 2;
    __shared__ __align__(16) char smem[2 * (ASZ + BSZ)];

    int t = threadIdx.x;
    int lane = t & 63, w = t >> 6;
    int wm = w >> 1, wn = w & 1;              // 2x2 wave grid: wave = 64(M) x WN(N)
    int lr = lane & 15, lq = lane >> 4;
    // XCD-aware tile remap (gridDim.y % 8 == 0 for all our launches)
    int gx = gridDim.x;
    int lin = blockIdx.x + gx * blockIdx.y;
    int li = lin >> 3;
    int qy = li / gx;
    int ty = (lin & 7) * (gridDim.y >> 3) + qy;
    int tx = li - qy * gx;
    int m0 = ty * 128, n0 = tx * TN;
    int swc = (lq ^ ((lr >> 1) & 3)) * 16;    // swizzled frag-read chunk offset

    // per-thread staging source pointers (bumped by BK each slab)
    const u16* ap[ACH];
    const u16* bp[BCH];
#pragma unroll
    for (int i = 0; i < ACH; i++) {
        int c = t + 256 * i, r = c / CPR, ww = c % CPR;
        int g = (ww & ~3) | ((ww & 3) ^ ((r >> 1) & 3));
        ap[i] = A + (size_t)(m0 + r) * K + g * 8;
    }
#pragma unroll
    for (int i = 0; i < BCH; i++) {
        int c = t + 256 * i, r = c / CPR, ww = c % CPR;
        int g = (ww & ~3) | ((ww & 3) ^ ((r >> 1) & 3));
        bp[i] = Bt + (size_t)(n0 + r) * K + g * 8;
    }

    f32x4 acc[4][NJ];
#pragma unroll
    for (int i = 0; i < 4; i++)
#pragma unroll
        for (int j = 0; j < NJ; j++) acc[i][j] = (f32x4){0.f, 0.f, 0.f, 0.f};

    // prologue: stage slab 0 into buffer 0
#pragma unroll
    for (int i = 0; i < ACH; i++)
        async16(smem + (t + 256 * i) * 16, ap[i]);
#pragma unroll
    for (int i = 0; i < BCH; i++)
        async16(smem + 2 * ASZ + (t + 256 * i) * 16, bp[i]);

    int nk = K / BK;
    for (int kt = 0; kt < nk; kt++) {
        int cur = kt & 1;
        __syncthreads();                      // slab kt ready; other buffer free
        if (kt + 1 < nk) {                    // prefetch slab kt+1 (drains at next barrier)
            char* An = smem + (1 - cur) * ASZ;
            char* Bn = smem + 2 * ASZ + (1 - cur) * BSZ;
#pragma unroll
            for (int i = 0; i < ACH; i++) {
                ap[i] += BK;
                async16(An + (t + 256 * i) * 16, ap[i]);
            }
#pragma unroll
            for (int i = 0; i < BCH; i++) {
                bp[i] += BK;
                async16(Bn + (t + 256 * i) * 16, bp[i]);
            }
        }
        const char* Ac = smem + cur * ASZ;
        const char* Bc = smem + 2 * ASZ + cur * BSZ;
#pragma unroll
        for (int h = 0; h < KH; h++) {
            bf16x8 af[4], bfr[NJ];
#pragma unroll
            for (int i = 0; i < 4; i++)
                af[i] = *(const bf16x8*)(Ac + (wm * 64 + i * 16 + lr) * (2 * BK) + h * 64 + swc);
#pragma unroll
            for (int j = 0; j < NJ; j++)
                bfr[j] = *(const bf16x8*)(Bc + (wn * WN + j * 16 + lr) * (2 * BK) + h * 64 + swc);
#pragma unroll
            for (int i = 0; i < 4; i++)
#pragma unroll
                for (int j = 0; j < NJ; j++)
                    acc[i][j] = __builtin_amdgcn_mfma_f32_16x16x32_bf16(af[i], bfr[j], acc[i][j], 0, 0, 0);
        }
    }

#pragma unroll
    for (int i = 0; i < 4; i++) {
        int rowb = m0 + wm * 64 + i * 16 + lq * 4;
#pragma unroll
        for (int j = 0; j < NJ; j++) {
            int col = n0 + wn * WN + j * 16 + lr;
            float bs = bias[col];
            float vals[4];
#pragma unroll
            for (int r = 0; r < 4; r++) vals[r] = acc[i][j][r] + bs;
            if (EPI == EPI_F32RES) {
#pragma unroll
                for (int r = 0; r < 4; r++) {
                    int rr = rowb + r;
                    Cf[(size_t)rr * N + col] = vals[r] + res[(size_t)rr * N + col];
                }
            } else if (EPI == EPI_GELU) {
#pragma unroll
                for (int r = 0; r < 4; r++) {
                    float v = vals[r];
                    v = 0.5f * v * (1.f + erff(v * 0.70710678118654752f));
                    Cb[(size_t)(rowb + r) * N + col] = f2bf(v);
                }
            } else { // QKV scatter: Q/K [bh][seq][64] (Q pre-scaled), V [bh][64][seq]
                int comp = col >> 10, cw = col & 1023;
                int h = cw >> 6, d = cw & 63;
                int bb0 = rowb >> 11, ts = rowb & 2047;   // rowb%4==0: no batch crossing
                int bh = bb0 * NH + h;
                if (comp == 0) {
#pragma unroll
                    for (int r = 0; r < 4; r++)
                        qb[((size_t)bh * SEQ + ts + r) * HDIM + d] = f2bf(vals[r] * QSCALE);
                } else if (comp == 1) {
#pragma unroll
                    for (int r = 0; r < 4; r++)
                        kb[((size_t)bh * SEQ + ts + r) * HDIM + d] = f2bf(vals[r]);
                } else {
                    ushort4 pk;
                    pk.x = f2bf(vals[0]); pk.y = f2bf(vals[1]);
                    pk.z = f2bf(vals[2]); pk.w = f2bf(vals[3]);
                    *(ushort4*)&vb[((size_t)bh * HDIM + d) * SEQ + ts] = pk;
                }
            }
        }
    }
}

// ---------------- flash attention v3: XCD-clustered heads, perm-packed P -------
// qb/kb: [bh][seq][64] bf16 (q pre-scaled by QSCALE); vb: [bh][64][seq] bf16
// Block remap: all 16 q-blocks of a head (4 heads per XCD) on one XCD -> K/V hit
// that XCD's L2. Each block: q-tile pair (31-bx, bx) -> 33 balanced iterations.
// LDS 40KB: QP (Q tile, reused as P buffer) + K dbuf + V dbuf, all XOR-swizzled:
//   chunk g (16B) of row r lives at byte r*128 + ((g ^ (r&7))*16).
__global__ __launch_bounds__(256, 4) void attn_mfma(const u16* __restrict__ qb,
                                                    const u16* __restrict__ kb,
                                                    const u16* __restrict__ vb,
                                                    u16* __restrict__ ctx)
{
    __shared__ __align__(16) char smem[40960];
    char* QP = smem;                        // 8KB Q tile / P buffer (wave-private rows)
    // XCD-cluster remap: lin%8 = XCD (dispatch heuristic); 4 heads per XCD
    int lin = blockIdx.x + 16 * blockIdx.y;
    int xcd = lin & 7, idx = lin >> 3;
    int bh = xcd + 8 * (idx & 3);
    int bx = idx >> 2;
    int bb = bh >> 4, h = bh & 15;
    int t = threadIdx.x, lane = t & 63, w = t >> 6;
    int lr = lane & 15, lq = lane >> 4;
    int sw = (lr & 7) * 16;                 // read-side swizzle
    int cA = (lq * 16) ^ sw;                // chunk lq   (k-half 0)
    int cB = (64 | (lq * 16)) ^ sw;         // chunk 4+lq (k-half 1)
    // staging: thread covers LDS chunks t and t+256; swizzled global source
    int c0 = t,        r0 = c0 >> 3, g0 = (c0 & 7) ^ (r0 & 7);
    int c1 = t + 256,  r1 = c1 >> 3, g1 = (c1 & 7) ^ (r1 & 7);
    size_t off0  = (size_t)r0 * 128  + g0 * 16;   // Q/K tiles: 128B per row
    size_t off1  = (size_t)r1 * 128  + g1 * 16;
    size_t voff0 = (size_t)r0 * 4096 + g0 * 16;   // V: row=d, global stride 4096B
    size_t voff1 = (size_t)r1 * 4096 + g1 * 16;

    const char* qg_base = (const char*)qb + (size_t)bh * SEQ * 128;
    const char* kg_base = (const char*)kb + (size_t)bh * SEQ * 128;
    const char* vg_base = (const char*)vb + (size_t)bh * 64 * 4096;

    for (int pass = 0; pass < 2; ++pass) {
        int qt = pass ? bx : (31 - bx);
        if (pass) __syncthreads();          // QP/K0/V0 free before re-staging
        const char* qg = qg_base + (size_t)qt * 8192;
        async16(QP + c0 * 16, qg + off0);
        async16(QP + c1 * 16, qg + off1);
        async16(smem + 8192 + c0 * 16, kg_base + off0);
        async16(smem + 8192 + c1 * 16, kg_base + off1);
        async16(smem + 24576 + c0 * 16, vg_base + voff0);
        async16(smem + 24576 + c1 * 16, vg_base + voff1);

        float mold = -INFINITY, lsum = 0.f;
        f32x4 o[4];
#pragma unroll
        for (int dj = 0; dj < 4; dj++) o[dj] = (f32x4){0.f, 0.f, 0.f, 0.f};
        bf16x8 bq0, bq1;

        for (int kt = 0; kt <= qt; ++kt) {
            int cur = kt & 1;
            __syncthreads();                // tile kt ready; other buf free
            if (kt < qt) {                  // prefetch kt+1 (drained at next barrier)
                const char* kgn = kg_base + (size_t)(kt + 1) * 8192;
                const char* vgn = vg_base + (size_t)(kt + 1) * 128;
                char* Kn = smem + 8192  + (1 - cur) * 8192;
                char* Vn = smem + 24576 + (1 - cur) * 8192;
                async16(Kn + c0 * 16, kgn + off0);
                async16(Kn + c1 * 16, kgn + off1);
                async16(Vn + c0 * 16, vgn + voff0);
                async16(Vn + c1 * 16, vgn + voff1);
            }
            if (kt == 0) {                  // Q frags -> regs (QP then reused as P)
                const char* qr = QP + (w * 16 + lr) * 128;
                bq0 = *(const bf16x8*)(qr + cA);
                bq1 = *(const bf16x8*)(qr + cB);
            }
            const char* Kc = smem + 8192  + cur * 8192;
            const char* Vc = smem + 24576 + cur * 8192;

            // S^T = K Q^T : lane holds keys j*16+lq*4+r (rows), q = w*16+lr (col)
            float sv[4][4];
            bool diag = (kt == qt);
#pragma unroll
            for (int j = 0; j < 4; ++j) {
                const char* kr = Kc + (j * 16 + lr) * 128;
                bf16x8 ak0 = *(const bf16x8*)(kr + cA);
                bf16x8 ak1 = *(const bf16x8*)(kr + cB);
                f32x4 z = (f32x4){0.f, 0.f, 0.f, 0.f};
                z = __builtin_amdgcn_mfma_f32_16x16x32_bf16(ak0, bq0, z, 0, 0, 0);
                z = __builtin_amdgcn_mfma_f32_16x16x32_bf16(ak1, bq1, z, 0, 0, 0);
#pragma unroll
                for (int r = 0; r < 4; r++) {
                    float xv = z[r];
                    if (diag && (j * 16 + lq * 4 + r > w * 16 + lr)) xv = -INFINITY;
                    sv[j][r] = xv;
                }
            }
            // online softmax in exp2 domain; one q per lane
            float mx = sv[0][0];
#pragma unroll
            for (int j = 0; j < 4; j++)
#pragma unroll
                for (int r = 0; r < 4; r++) mx = fmaxf(mx, sv[j][r]);
            mx = fmaxf(mx, __shfl_xor(mx, 16));
            mx = fmaxf(mx, __shfl_xor(mx, 32));
            float mnew = fmaxf(mold, mx);
            float alpha = exp2f(mold - mnew);
            float rs = 0.f;
            unsigned pk[4][2];
#pragma unroll
            for (int j = 0; j < 4; j++)
#pragma unroll
                for (int hh = 0; hh < 2; hh++) {
                    float p0 = exp2f(sv[j][2 * hh]     - mnew);
                    float p1 = exp2f(sv[j][2 * hh + 1] - mnew);
                    rs += p0 + p1;
                    union { float f; unsigned u; } a0, a1;
                    a0.f = p0; a1.f = p1;
                    // truncation-pack: D = {hi16(p1), hi16(p0)} in ONE v_perm_b32
                    pk[j][hh] = __builtin_amdgcn_perm(a1.u, a0.u, 0x07060302u);
                }
            rs += __shfl_xor(rs, 16);
            rs += __shfl_xor(rs, 32);
            lsum = lsum * alpha + rs;
            mold = mnew;
#pragma unroll
            for (int dj = 0; dj < 4; dj++)
#pragma unroll
                for (int r = 0; r < 4; r++) o[dj][r] *= alpha;

            // P^T -> LDS (wave-private rows; no barrier): row q=w*16+lr, b64 writes
            {
                char* pw = QP + (w * 16 + lr) * 128 + (lq & 1) * 8;
#pragma unroll
                for (int j = 0; j < 4; j++) {
                    int pos = ((j * 2 + (lq >> 1)) * 16) ^ sw;
                    uint2 u; u.x = pk[j][0]; u.y = pk[j][1];
                    *(uint2*)(pw + pos) = u;
                }
            }
            asm volatile("s_waitcnt lgkmcnt(0)" ::: "memory");
            const char* pr = QP + (w * 16 + lr) * 128;
            bf16x8 bp0 = *(const bf16x8*)(pr + cA);
            bf16x8 bp1 = *(const bf16x8*)(pr + cB);
            // O^T += V^T P^T : rows d, cols q
#pragma unroll
            for (int dj = 0; dj < 4; ++dj) {
                const char* vr = Vc + (dj * 16 + lr) * 128;
                bf16x8 av0 = *(const bf16x8*)(vr + cA);
                bf16x8 av1 = *(const bf16x8*)(vr + cB);
                o[dj] = __builtin_amdgcn_mfma_f32_16x16x32_bf16(av0, bp0, o[dj], 0, 0, 0);
                o[dj] = __builtin_amdgcn_mfma_f32_16x16x32_bf16(av1, bp1, o[dj], 0, 0, 0);
            }
        }

        float inv = 1.f / lsum;
        int tok = qt * 64 + w * 16 + lr;
        u16* cp = ctx + ((size_t)(bb * SEQ) + tok) * TD + h * HDIM + lq * 4;
#pragma unroll
        for (int dj = 0; dj < 4; dj++) {
            ushort4 s4;
            s4.x = f2bf(o[dj][0] * inv); s4.y = f2bf(o[dj][1] * inv);
            s4.z = f2bf(o[dj][2] * inv); s4.w = f2bf(o[dj][3] * inv);
            *(ushort4*)(cp + dj * 16) = s4;
        }
    }
}

extern "C" void kernel_launch(void* const* d_in, const int* in_sizes, int n_in,
                              void* d_out, int out_size, void* d_ws, size_t ws_size,
                              hipStream_t stream)
{
    const float* x    = (const float*)d_in[0];
    const float* g1   = (const float*)d_in[1];
    const float* b1   = (const float*)d_in[2];
    const float* Wqkv = (const float*)d_in[3];
    const float* bqkv = (const float*)d_in[4];
    const float* Wo   = (const float*)d_in[5];
    const float* bo   = (const float*)d_in[6];
    const float* g2   = (const float*)d_in[7];
    const float* b2   = (const float*)d_in[8];
    const float* W1   = (const float*)d_in[9];
    const float* b1f  = (const float*)d_in[10];
    const float* W2   = (const float*)d_in[11];
    const float* b2f  = (const float*)d_in[12];
    float* out = (float*)d_out;

    char* ws = (char*)d_ws;
    const size_t MB = 1ull << 20;
    u16* wqkvT = (u16*)(ws + 0 * MB);    // 6 MB  [3072][1024]
    u16* woT   = (u16*)(ws + 6 * MB);    // 2 MB  [1024][1024]
    u16* w1T   = (u16*)(ws + 8 * MB);    // 8 MB  [4096][1024]
    u16* w2T   = (u16*)(ws + 16 * MB);   // 8 MB  [1024][4096]
    u16* qbuf  = (u16*)(ws + 24 * MB);   // 8 MB  [32][2048][64] (pre-scaled)
    u16* kbuf  = (u16*)(ws + 32 * MB);   // 8 MB
    u16* vbuf  = (u16*)(ws + 40 * MB);   // 8 MB  [32][64][2048]
    u16* hbuf  = (u16*)(ws + 48 * MB);   // 8 MB  h then hh
    u16* ctx   = (u16*)(ws + 56 * MB);   // 8 MB
    float* x2  = (float*)(ws + 64 * MB); // 16 MB
    u16* ff1   = (u16*)(ws + 80 * MB);   // 32 MB  -> 112 MB total

    // fused: weight transposes + LN1 (independent work, one dispatch)
    prep_kernel<<<3072 + NROWS, 256, 0, stream>>>(
        Wqkv, Wo, W1, W2, wqkvT, woT, w1T, w2T, x, g1, b1, hbuf);

    gemm_mfma<EPI_QKV, 128, 64><<<dim3(3 * TD / 128, NROWS / 128), 256, 0, stream>>>(
        NROWS, 3 * TD, TD, hbuf, wqkvT, bqkv, nullptr, nullptr, nullptr, qbuf, kbuf, vbuf);
    attn_mfma<<<dim3(16, NB * NH), 256, 0, stream>>>(qbuf, kbuf, vbuf, ctx);
    gemm_mfma<EPI_F32RES, 64, 64><<<dim3(TD / 64, NROWS / 128), 256, 0, stream>>>(
        NROWS, TD, TD, ctx, woT, bo, x, x2, nullptr, nullptr, nullptr, nullptr);
    ln_bf16<<<NROWS, 256, 0, stream>>>(x2, g2, b2, hbuf);
    gemm_mfma<EPI_GELU, 128, 64><<<dim3(FFD / 128, NROWS / 128), 256, 0, stream>>>(
        NROWS, FFD, TD, hbuf, w1T, b1f, nullptr, nullptr, ff1, nullptr, nullptr, nullptr);
    gemm_mfma<EPI_F32RES, 64, 64><<<dim3(TD / 64, NROWS / 128), 256, 0, stream>>>(
        NROWS, TD, FFD, ff1, w2T, b2f, x2, out, nullptr, nullptr, nullptr, nullptr);
}

// Round 9
// 308.571 us; speedup vs baseline: 7.0016x; 1.0631x over previous
//
#include <hip/hip_runtime.h>
#include <math.h>

#define TD 1024      // model dim
#define NH 16        // heads
#define HDIM 64      // head dim
#define SEQ 2048     // seq len
#define NB 2         // batch
#define NROWS 4096   // NB*SEQ
#define FFD 4096     // ffn dim

// 1/sqrt(64) * log2(e): softmax computed in exp2 domain; folded into Q at QKV epilogue
#define QSCALE 0.18033688011112042f

typedef unsigned short u16;
typedef __attribute__((ext_vector_type(8))) short bf16x8;   // 8 bf16 = 4 VGPR
typedef __attribute__((ext_vector_type(4))) float f32x4;    // MFMA acc

__device__ __forceinline__ u16 f2bf(float f) {
    union { float f; unsigned u; } v; v.f = f;
    return (u16)((v.u + 0x7FFFu + ((v.u >> 16) & 1u)) >> 16);
}

// async global->LDS, 16B per lane. LDS dest must be wave-uniform base + lane*16.
__device__ __forceinline__ void async16(void* lds, const void* g) {
    __builtin_amdgcn_global_load_lds(
        (const __attribute__((address_space(1))) unsigned*)g,
        (__attribute__((address_space(3))) unsigned*)lds, 16, 0, 0);
}

// tanh-form GELU (max |err| vs exact erf-GELU ~3e-3; threshold headroom 4x)
__device__ __forceinline__ float gelu_f(float v) {
    float u = 0.7978845608028654f * (v + 0.044715f * v * v * v);
    float e = __expf(2.f * u);
    float th = 1.f - 2.f * __builtin_amdgcn_rcpf(e + 1.f);
    return 0.5f * v * (1.f + th);
}

// ---------------- LayerNorm -> bf16 out: one block per row of 1024 -------------
__global__ __launch_bounds__(256) void ln_bf16(const float* __restrict__ x,
                                               const float* __restrict__ g,
                                               const float* __restrict__ b,
                                               u16* __restrict__ out)
{
    int row = blockIdx.x;
    const float* xr = x + (size_t)row * TD;
    u16* outr = out + (size_t)row * TD;
    int t = threadIdx.x;
    float v[4];
    float s = 0.f, ss = 0.f;
#pragma unroll
    for (int i = 0; i < 4; i++) {
        v[i] = xr[t + 256 * i];
        s += v[i];
        ss += v[i] * v[i];
    }
#pragma unroll
    for (int o = 32; o > 0; o >>= 1) {
        s  += __shfl_down(s, o);
        ss += __shfl_down(ss, o);
    }
    __shared__ float sm[4], sm2[4];
    int wave = t >> 6, lane = t & 63;
    if (lane == 0) { sm[wave] = s; sm2[wave] = ss; }
    __syncthreads();
    s  = sm[0] + sm[1] + sm[2] + sm[3];
    ss = sm2[0] + sm2[1] + sm2[2] + sm2[3];
    float mu  = s * (1.f / TD);
    float var = ss * (1.f / TD) - mu * mu;
    float rstd = rsqrtf(var + 1e-5f);
#pragma unroll
    for (int i = 0; i < 4; i++) {
        int c = t + 256 * i;
        outr[c] = f2bf((v[i] - mu) * rstd * g[c] + b[c]);
    }
}

// --- prep: fused weight convert+transpose (blocks 0..3071) + LN1 (3072..7167) --
__global__ __launch_bounds__(256) void prep_kernel(
    const float* __restrict__ Wqkv, const float* __restrict__ Wo,
    const float* __restrict__ W1,   const float* __restrict__ W2,
    u16* __restrict__ wqkvT, u16* __restrict__ woT,
    u16* __restrict__ w1T,   u16* __restrict__ w2T,
    const float* __restrict__ x, const float* __restrict__ g1,
    const float* __restrict__ b1, u16* __restrict__ hbuf)
{
    int blk = blockIdx.x;
    int t = threadIdx.x;
    if (blk >= 3072) {               // ---- LN1 path ----
        int row = blk - 3072;
        const float* xr = x + (size_t)row * TD;
        u16* outr = hbuf + (size_t)row * TD;
        float v[4];
        float s = 0.f, ss = 0.f;
#pragma unroll
        for (int i = 0; i < 4; i++) {
            v[i] = xr[t + 256 * i];
            s += v[i];
            ss += v[i] * v[i];
        }
#pragma unroll
        for (int o = 32; o > 0; o >>= 1) {
            s  += __shfl_down(s, o);
            ss += __shfl_down(ss, o);
        }
        __shared__ float sm[4], sm2[4];
        int wave = t >> 6, lane = t & 63;
        if (lane == 0) { sm[wave] = s; sm2[wave] = ss; }
        __syncthreads();
        s  = sm[0] + sm[1] + sm[2] + sm[3];
        ss = sm2[0] + sm2[1] + sm2[2] + sm2[3];
        float mu  = s * (1.f / TD);
        float var = ss * (1.f / TD) - mu * mu;
        float rstd = rsqrtf(var + 1e-5f);
#pragma unroll
        for (int i = 0; i < 4; i++) {
            int c = t + 256 * i;
            outr[c] = f2bf((v[i] - mu) * rstd * g1[c] + b1[c]);
        }
        return;
    }
    // ---- weight transpose path ----
    const float* W; u16* Wt; int K, N, local, nx;
    if (blk < 768)       { W = Wqkv; Wt = wqkvT; K = TD;  N = 3 * TD; local = blk;        nx = 48; }
    else if (blk < 1024) { W = Wo;   Wt = woT;   K = TD;  N = TD;     local = blk - 768;  nx = 16; }
    else if (blk < 2048) { W = W1;   Wt = w1T;   K = TD;  N = FFD;    local = blk - 1024; nx = 64; }
    else                 { W = W2;   Wt = w2T;   K = FFD; N = TD;     local = blk - 2048; nx = 16; }
    int n0 = (local % nx) * 64, k0 = (local / nx) * 64;
    __shared__ u16 tile[64][65];
    int c = t & 63, rq = t >> 6;
#pragma unroll
    for (int i = 0; i < 16; i++) {
        int r = rq * 16 + i;
        tile[r][c] = f2bf(W[(size_t)(k0 + r) * N + n0 + c]);
    }
    __syncthreads();
#pragma unroll
    for (int i = 0; i < 16; i++) {
        int r = rq * 16 + i;
        Wt[(size_t)(n0 + r) * K + k0 + c] = tile[c][r];
    }
}

// ---------------- bf16 MFMA GEMM: 128xTN tile, BK=64 k-slab, dbuf LDS ----------
// C[M,N] = A[M,K] @ Bt[N,K]^T + bias, with epilogues.
// Pipeline: one barrier per K-step; prefetch of slab k+1 issued right AFTER the
// barrier that publishes slab k -> vmcnt(0) drain at the next barrier waits on
// loads that had a full compute phase in flight.
// LDS swizzle (full 3-bit, 128B rows): 16B chunk g of row r stored at slot
// g ^ (r&7). Frag read k-half h: offset ((lq^(lr&7))*16) ^ (h*64) -> 64 lanes
// spread 8 lanes per granule = structural minimum, 0 conflicts.
// XCD swizzle: tiles remapped so all N-tiles of an M-row land on one XCD's L2.
#define EPI_QKV 0
#define EPI_F32RES 1
#define EPI_GELU 2

template<int EPI, int TN, int BK>
__global__ __launch_bounds__(256) void gemm_mfma(int M, int N, int K,
    const u16* __restrict__ A, const u16* __restrict__ Bt,
    const float* __restrict__ bias, const float* __restrict__ res,
    float* __restrict__ Cf, u16* __restrict__ Cb,
    u16* __restrict__ qb, u16* __restrict__ kb, u16* __restrict__ vb)
{
    constexpr int WN  = TN / 2;               // per-wave N extent (2 waves along N)
    constexpr int NJ  = WN / 16;              // B frags per wave
    constexpr int KH  = BK / 32;              // 32-elem k-halves per slab
    constexpr int CPR = BK / 8;               // 16B chunks per tile-row (8)
    constexpr int ACH = (128 * CPR) / 256;    // A chunks per thread
    constexpr int BCH = (TN  * CPR) / 256;    // B chunks per thread
    constexpr int ASZ = 128 * BK * 2;         // bytes per A buffer
    constexpr int BSZ = TN  * BK * 2;
    __shared__ __align__(16) char smem[2 * (ASZ + BSZ)];

    int t = threadIdx.x;
    int lane = t & 63, w = t >> 6;
    int wm = w >> 1, wn = w & 1;              // 2x2 wave grid: wave = 64(M) x WN(N)
    int lr = lane & 15, lq = lane >> 4;
    // XCD-aware tile remap (gridDim.y % 8 == 0 for all our launches)
    int gx = gridDim.x;
    int lin = blockIdx.x + gx * blockIdx.y;
    int li = lin >> 3;
    int qy = li / gx;
    int ty = (lin & 7) * (gridDim.y >> 3) + qy;
    int tx = li - qy * gx;
    int m0 = ty * 128, n0 = tx * TN;
    int pg = (lq ^ (lr & (CPR - 1))) * 16;    // swizzled frag-read granule offset

    // per-thread staging source pointers (bumped by BK each slab)
    const u16* ap[ACH];
    const u16* bp[BCH];
#pragma unroll
    for (int i = 0; i < ACH; i++) {
        int c = t + 256 * i, r = c / CPR, s = c % CPR;
        int g = s ^ (r & (CPR - 1));
        ap[i] = A + (size_t)(m0 + r) * K + g * 8;
    }
#pragma unroll
    for (int i = 0; i < BCH; i++) {
        int c = t + 256 * i, r = c / CPR, s = c % CPR;
        int g = s ^ (r & (CPR - 1));
        bp[i] = Bt + (size_t)(n0 + r) * K + g * 8;
    }

    f32x4 acc[4][NJ];
#pragma unroll
    for (int i = 0; i < 4; i++)
#pragma unroll
        for (int j = 0; j < NJ; j++) acc[i][j] = (f32x4){0.f, 0.f, 0.f, 0.f};

    // prologue: stage slab 0 into buffer 0
#pragma unroll
    for (int i = 0; i < ACH; i++)
        async16(smem + (t + 256 * i) * 16, ap[i]);
#pragma unroll
    for (int i = 0; i < BCH; i++)
        async16(smem + 2 * ASZ + (t + 256 * i) * 16, bp[i]);

    int nk = K / BK;
    for (int kt = 0; kt < nk; kt++) {
        int cur = kt & 1;
        __syncthreads();                      // slab kt ready; other buffer free
        if (kt + 1 < nk) {                    // prefetch slab kt+1 (drains at next barrier)
            char* An = smem + (1 - cur) * ASZ;
            char* Bn = smem + 2 * ASZ + (1 - cur) * BSZ;
#pragma unroll
            for (int i = 0; i < ACH; i++) {
                ap[i] += BK;
                async16(An + (t + 256 * i) * 16, ap[i]);
            }
#pragma unroll
            for (int i = 0; i < BCH; i++) {
                bp[i] += BK;
                async16(Bn + (t + 256 * i) * 16, bp[i]);
            }
        }
        const char* Ac = smem + cur * ASZ;
        const char* Bc = smem + 2 * ASZ + cur * BSZ;
#pragma unroll
        for (int h = 0; h < KH; h++) {
            bf16x8 af[4], bfr[NJ];
#pragma unroll
            for (int i = 0; i < 4; i++)
                af[i] = *(const bf16x8*)(Ac + (wm * 64 + i * 16 + lr) * (2 * BK) + (pg ^ (h * 64)));
#pragma unroll
            for (int j = 0; j < NJ; j++)
                bfr[j] = *(const bf16x8*)(Bc + (wn * WN + j * 16 + lr) * (2 * BK) + (pg ^ (h * 64)));
#pragma unroll
            for (int i = 0; i < 4; i++)
#pragma unroll
                for (int j = 0; j < NJ; j++)
                    acc[i][j] = __builtin_amdgcn_mfma_f32_16x16x32_bf16(af[i], bfr[j], acc[i][j], 0, 0, 0);
        }
    }

#pragma unroll
    for (int i = 0; i < 4; i++) {
        int rowb = m0 + wm * 64 + i * 16 + lq * 4;
#pragma unroll
        for (int j = 0; j < NJ; j++) {
            int col = n0 + wn * WN + j * 16 + lr;
            float bs = bias[col];
            float vals[4];
#pragma unroll
            for (int r = 0; r < 4; r++) vals[r] = acc[i][j][r] + bs;
            if (EPI == EPI_F32RES) {
#pragma unroll
                for (int r = 0; r < 4; r++) {
                    int rr = rowb + r;
                    Cf[(size_t)rr * N + col] = vals[r] + res[(size_t)rr * N + col];
                }
            } else if (EPI == EPI_GELU) {
#pragma unroll
                for (int r = 0; r < 4; r++)
                    Cb[(size_t)(rowb + r) * N + col] = f2bf(gelu_f(vals[r]));
            } else { // QKV scatter: Q/K [bh][seq][64] (Q pre-scaled), V [bh][64][seq]
                int comp = col >> 10, cw = col & 1023;
                int h = cw >> 6, d = cw & 63;
                int bb0 = rowb >> 11, ts = rowb & 2047;   // rowb%4==0: no batch crossing
                int bh = bb0 * NH + h;
                if (comp == 0) {
#pragma unroll
                    for (int r = 0; r < 4; r++)
                        qb[((size_t)bh * SEQ + ts + r) * HDIM + d] = f2bf(vals[r] * QSCALE);
                } else if (comp == 1) {
#pragma unroll
                    for (int r = 0; r < 4; r++)
                        kb[((size_t)bh * SEQ + ts + r) * HDIM + d] = f2bf(vals[r]);
                } else {
                    ushort4 pk;
                    pk.x = f2bf(vals[0]); pk.y = f2bf(vals[1]);
                    pk.z = f2bf(vals[2]); pk.w = f2bf(vals[3]);
                    *(ushort4*)&vb[((size_t)bh * HDIM + d) * SEQ + ts] = pk;
                }
            }
        }
    }
}

// ---------------- flash attention v3: XCD-clustered heads, perm-packed P -------
// qb/kb: [bh][seq][64] bf16 (q pre-scaled by QSCALE); vb: [bh][64][seq] bf16
// Block remap: all 16 q-blocks of a head (4 heads per XCD) on one XCD -> K/V hit
// that XCD's L2. Each block: q-tile pair (31-bx, bx) -> 33 balanced iterations.
// LDS 40KB: QP (Q tile, reused as P buffer) + K dbuf + V dbuf, all XOR-swizzled:
//   chunk g (16B) of row r lives at byte r*128 + ((g ^ (r&7))*16).
__global__ __launch_bounds__(256, 4) void attn_mfma(const u16* __restrict__ qb,
                                                    const u16* __restrict__ kb,
                                                    const u16* __restrict__ vb,
                                                    u16* __restrict__ ctx)
{
    __shared__ __align__(16) char smem[40960];
    char* QP = smem;                        // 8KB Q tile / P buffer (wave-private rows)
    // XCD-cluster remap: lin%8 = XCD (dispatch heuristic); 4 heads per XCD
    int lin = blockIdx.x + 16 * blockIdx.y;
    int xcd = lin & 7, idx = lin >> 3;
    int bh = xcd + 8 * (idx & 3);
    int bx = idx >> 2;
    int bb = bh >> 4, h = bh & 15;
    int t = threadIdx.x, lane = t & 63, w = t >> 6;
    int lr = lane & 15, lq = lane >> 4;
    int sw = (lr & 7) * 16;                 // read-side swizzle
    int cA = (lq * 16) ^ sw;                // chunk lq   (k-half 0)
    int cB = (64 | (lq * 16)) ^ sw;         // chunk 4+lq (k-half 1)
    // staging: thread covers LDS chunks t and t+256; swizzled global source
    int c0 = t,        r0 = c0 >> 3, g0 = (c0 & 7) ^ (r0 & 7);
    int c1 = t + 256,  r1 = c1 >> 3, g1 = (c1 & 7) ^ (r1 & 7);
    size_t off0  = (size_t)r0 * 128  + g0 * 16;   // Q/K tiles: 128B per row
    size_t off1  = (size_t)r1 * 128  + g1 * 16;
    size_t voff0 = (size_t)r0 * 4096 + g0 * 16;   // V: row=d, global stride 4096B
    size_t voff1 = (size_t)r1 * 4096 + g1 * 16;

    const char* qg_base = (const char*)qb + (size_t)bh * SEQ * 128;
    const char* kg_base = (const char*)kb + (size_t)bh * SEQ * 128;
    const char* vg_base = (const char*)vb + (size_t)bh * 64 * 4096;

    for (int pass = 0; pass < 2; ++pass) {
        int qt = pass ? bx : (31 - bx);
        if (pass) __syncthreads();          // QP/K0/V0 free before re-staging
        const char* qg = qg_base + (size_t)qt * 8192;
        async16(QP + c0 * 16, qg + off0);
        async16(QP + c1 * 16, qg + off1);
        async16(smem + 8192 + c0 * 16, kg_base + off0);
        async16(smem + 8192 + c1 * 16, kg_base + off1);
        async16(smem + 24576 + c0 * 16, vg_base + voff0);
        async16(smem + 24576 + c1 * 16, vg_base + voff1);

        float mold = -INFINITY, lsum = 0.f;
        f32x4 o[4];
#pragma unroll
        for (int dj = 0; dj < 4; dj++) o[dj] = (f32x4){0.f, 0.f, 0.f, 0.f};
        bf16x8 bq0, bq1;

        for (int kt = 0; kt <= qt; ++kt) {
            int cur = kt & 1;
            __syncthreads();                // tile kt ready; other buf free
            if (kt < qt) {                  // prefetch kt+1 (drained at next barrier)
                const char* kgn = kg_base + (size_t)(kt + 1) * 8192;
                const char* vgn = vg_base + (size_t)(kt + 1) * 128;
                char* Kn = smem + 8192  + (1 - cur) * 8192;
                char* Vn = smem + 24576 + (1 - cur) * 8192;
                async16(Kn + c0 * 16, kgn + off0);
                async16(Kn + c1 * 16, kgn + off1);
                async16(Vn + c0 * 16, vgn + voff0);
                async16(Vn + c1 * 16, vgn + voff1);
            }
            if (kt == 0) {                  // Q frags -> regs (QP then reused as P)
                const char* qr = QP + (w * 16 + lr) * 128;
                bq0 = *(const bf16x8*)(qr + cA);
                bq1 = *(const bf16x8*)(qr + cB);
            }
            const char* Kc = smem + 8192  + cur * 8192;
            const char* Vc = smem + 24576 + cur * 8192;

            // S^T = K Q^T : lane holds keys j*16+lq*4+r (rows), q = w*16+lr (col)
            float sv[4][4];
            bool diag = (kt == qt);
#pragma unroll
            for (int j = 0; j < 4; ++j) {
                const char* kr = Kc + (j * 16 + lr) * 128;
                bf16x8 ak0 = *(const bf16x8*)(kr + cA);
                bf16x8 ak1 = *(const bf16x8*)(kr + cB);
                f32x4 z = (f32x4){0.f, 0.f, 0.f, 0.f};
                z = __builtin_amdgcn_mfma_f32_16x16x32_bf16(ak0, bq0, z, 0, 0, 0);
                z = __builtin_amdgcn_mfma_f32_16x16x32_bf16(ak1, bq1, z, 0, 0, 0);
#pragma unroll
                for (int r = 0; r < 4; r++) {
                    float xv = z[r];
                    if (diag && (j * 16 + lq * 4 + r > w * 16 + lr)) xv = -INFINITY;
                    sv[j][r] = xv;
                }
            }
            // online softmax in exp2 domain; one q per lane
            float mx = sv[0][0];
#pragma unroll
            for (int j = 0; j < 4; j++)
#pragma unroll
                for (int r = 0; r < 4; r++) mx = fmaxf(mx, sv[j][r]);
            mx = fmaxf(mx, __shfl_xor(mx, 16));
            mx = fmaxf(mx, __shfl_xor(mx, 32));
            float mnew = fmaxf(mold, mx);
            float alpha = exp2f(mold - mnew);
            float rs = 0.f;
            unsigned pk[4][2];
#pragma unroll
            for (int j = 0; j < 4; j++)
#pragma unroll
                for (int hh = 0; hh < 2; hh++) {
                    float p0 = exp2f(sv[j][2 * hh]     - mnew);
                    float p1 = exp2f(sv[j][2 * hh + 1] - mnew);
                    rs += p0 + p1;
                    union { float f; unsigned u; } a0, a1;
                    a0.f = p0; a1.f = p1;
                    // truncation-pack: D = {hi16(p1), hi16(p0)} in ONE v_perm_b32
                    pk[j][hh] = __builtin_amdgcn_perm(a1.u, a0.u, 0x07060302u);
                }
            rs += __shfl_xor(rs, 16);
            rs += __shfl_xor(rs, 32);
            lsum = lsum * alpha + rs;
            mold = mnew;
#pragma unroll
            for (int dj = 0; dj < 4; dj++)
#pragma unroll
                for (int r = 0; r < 4; r++) o[dj][r] *= alpha;

            // P^T -> LDS (wave-private rows; no barrier): row q=w*16+lr, b64 writes
            {
                char* pw = QP + (w * 16 + lr) * 128 + (lq & 1) * 8;
#pragma unroll
                for (int j = 0; j < 4; j++) {
                    int pos = ((j * 2 + (lq >> 1)) * 16) ^ sw;
                    uint2 u; u.x = pk[j][0]; u.y = pk[j][1];
                    *(uint2*)(pw + pos) = u;
                }
            }
            asm volatile("s_waitcnt lgkmcnt(0)" ::: "memory");
            const char* pr = QP + (w * 16 + lr) * 128;
            bf16x8 bp0 = *(const bf16x8*)(pr + cA);
            bf16x8 bp1 = *(const bf16x8*)(pr + cB);
            // O^T += V^T P^T : rows d, cols q
#pragma unroll
            for (int dj = 0; dj < 4; ++dj) {
                const char* vr = Vc + (dj * 16 + lr) * 128;
                bf16x8 av0 = *(const bf16x8*)(vr + cA);
                bf16x8 av1 = *(const bf16x8*)(vr + cB);
                o[dj] = __builtin_amdgcn_mfma_f32_16x16x32_bf16(av0, bp0, o[dj], 0, 0, 0);
                o[dj] = __builtin_amdgcn_mfma_f32_16x16x32_bf16(av1, bp1, o[dj], 0, 0, 0);
            }
        }

        float inv = 1.f / lsum;
        int tok = qt * 64 + w * 16 + lr;
        u16* cp = ctx + ((size_t)(bb * SEQ) + tok) * TD + h * HDIM + lq * 4;
#pragma unroll
        for (int dj = 0; dj < 4; dj++) {
            ushort4 s4;
            s4.x = f2bf(o[dj][0] * inv); s4.y = f2bf(o[dj][1] * inv);
            s4.z = f2bf(o[dj][2] * inv); s4.w = f2bf(o[dj][3] * inv);
            *(ushort4*)(cp + dj * 16) = s4;
        }
    }
}

extern "C" void kernel_launch(void* const* d_in, const int* in_sizes, int n_in,
                              void* d_out, int out_size, void* d_ws, size_t ws_size,
                              hipStream_t stream)
{
    const float* x    = (const float*)d_in[0];
    const float* g1   = (const float*)d_in[1];
    const float* b1   = (const float*)d_in[2];
    const float* Wqkv = (const float*)d_in[3];
    const float* bqkv = (const float*)d_in[4];
    const float* Wo   = (const float*)d_in[5];
    const float* bo   = (const float*)d_in[6];
    const float* g2   = (const float*)d_in[7];
    const float* b2   = (const float*)d_in[8];
    const float* W1   = (const float*)d_in[9];
    const float* b1f  = (const float*)d_in[10];
    const float* W2   = (const float*)d_in[11];
    const float* b2f  = (const float*)d_in[12];
    float* out = (float*)d_out;

    char* ws = (char*)d_ws;
    const size_t MB = 1ull << 20;
    u16* wqkvT = (u16*)(ws + 0 * MB);    // 6 MB  [3072][1024]
    u16* woT   = (u16*)(ws + 6 * MB);    // 2 MB  [1024][1024]
    u16* w1T   = (u16*)(ws + 8 * MB);    // 8 MB  [4096][1024]
    u16* w2T   = (u16*)(ws + 16 * MB);   // 8 MB  [1024][4096]
    u16* qbuf  = (u16*)(ws + 24 * MB);   // 8 MB  [32][2048][64] (pre-scaled)
    u16* kbuf  = (u16*)(ws + 32 * MB);   // 8 MB
    u16* vbuf  = (u16*)(ws + 40 * MB);   // 8 MB  [32][64][2048]
    u16* hbuf  = (u16*)(ws + 48 * MB);   // 8 MB  h then hh
    u16* ctx   = (u16*)(ws + 56 * MB);   // 8 MB
    float* x2  = (float*)(ws + 64 * MB); // 16 MB
    u16* ff1   = (u16*)(ws + 80 * MB);   // 32 MB  -> 112 MB total

    // fused: weight transposes + LN1 (independent work, one dispatch)
    prep_kernel<<<3072 + NROWS, 256, 0, stream>>>(
        Wqkv, Wo, W1, W2, wqkvT, woT, w1T, w2T, x, g1, b1, hbuf);

    gemm_mfma<EPI_QKV, 128, 64><<<dim3(3 * TD / 128, NROWS / 128), 256, 0, stream>>>(
        NROWS, 3 * TD, TD, hbuf, wqkvT, bqkv, nullptr, nullptr, nullptr, qbuf, kbuf, vbuf);
    attn_mfma<<<dim3(16, NB * NH), 256, 0, stream>>>(qbuf, kbuf, vbuf, ctx);
    gemm_mfma<EPI_F32RES, 64, 64><<<dim3(TD / 64, NROWS / 128), 256, 0, stream>>>(
        NROWS, TD, TD, ctx, woT, bo, x, x2, nullptr, nullptr, nullptr, nullptr);
    ln_bf16<<<NROWS, 256, 0, stream>>>(x2, g2, b2, hbuf);
    gemm_mfma<EPI_GELU, 128, 64><<<dim3(FFD / 128, NROWS / 128), 256, 0, stream>>>(
        NROWS, FFD, TD, hbuf, w1T, b1f, nullptr, nullptr, ff1, nullptr, nullptr, nullptr);
    gemm_mfma<EPI_F32RES, 64, 64><<<dim3(TD / 64, NROWS / 128), 256, 0, stream>>>(
        NROWS, TD, FFD, ff1, w2T, b2f, x2, out, nullptr, nullptr, nullptr, nullptr);
}